// Round 1
// baseline (1199.582 us; speedup 1.0000x reference)
//
#include <hip/hip_runtime.h>
#include <hip/hip_bf16.h>
#include <math.h>

// ---------------- degree / normalization ----------------

__global__ void init_deg_kernel(float* deg, int N) {
    int i = blockIdx.x * blockDim.x + threadIdx.x;
    if (i < N) deg[i] = 1.0f;  // self-loop
}

__global__ void accum_deg_kernel(const int* __restrict__ col, float* deg, int E) {
    int e = blockIdx.x * blockDim.x + threadIdx.x;
    if (e < E) atomicAdd(&deg[col[e]], 1.0f);
}

__global__ void to_dis_kernel(float* deg, int N) {
    int i = blockIdx.x * blockDim.x + threadIdx.x;
    if (i < N) deg[i] = rsqrtf(deg[i]);
}

// ---------------- dense GEMM: H[n][m] = sum_k X[n][k] * W[k][m], K=128 ----------------
// M: true output cols; MP: padded (power-of-2-ish) thread mapping; BN rows per block.
template<int M, int MP, int BN>
__global__ void gemm_kernel(const float* __restrict__ X, const float* __restrict__ W,
                            float* __restrict__ H, int N) {
    __shared__ float Xs[BN][128];
    const int nThreads = 256;
    int n0 = blockIdx.x * BN;
    int tid = threadIdx.x;

    for (int i = tid; i < BN * 128; i += nThreads) {
        int r = i >> 7, k = i & 127;
        int n = n0 + r;
        Xs[r][k] = (n < N) ? X[(size_t)n * 128 + k] : 0.0f;
    }
    __syncthreads();

    int m = tid % MP;
    int r0 = tid / MP;
    constexpr int RSTRIDE = nThreads / MP;
    constexpr int RPT = BN / RSTRIDE;

    if (m < M) {
        float acc[RPT];
#pragma unroll
        for (int i = 0; i < RPT; i++) acc[i] = 0.0f;

        for (int k = 0; k < 128; k++) {
            float wk = W[(size_t)k * M + m];
#pragma unroll
            for (int i = 0; i < RPT; i++)
                acc[i] += Xs[r0 + i * RSTRIDE][k] * wk;
        }
#pragma unroll
        for (int i = 0; i < RPT; i++) {
            int n = n0 + r0 + i * RSTRIDE;
            if (n < N) H[(size_t)n * M + m] = acc[i];
        }
    }
}

// ---------------- self-loop init: out[i][f] = H[i][f] * dis[i]^2 ----------------
template<int F>
__global__ void init_self_kernel(const float* __restrict__ H, const float* __restrict__ dis,
                                 float* __restrict__ out, int N) {
    long total = (long)N * F;
    for (long idx = (long)blockIdx.x * blockDim.x + threadIdx.x; idx < total;
         idx += (long)gridDim.x * blockDim.x) {
        int i = (int)(idx / F);
        float d = dis[i];
        out[idx] = H[idx] * d * d;
    }
}

// ---------------- edge aggregation: out[c][f] += H[r][f]*dis[r]*dis[c] ----------------
template<int F>
__global__ void agg_kernel(const float* __restrict__ H, const int* __restrict__ row,
                           const int* __restrict__ col, const float* __restrict__ dis,
                           float* out, int E) {
    long total = (long)E * F;
    for (long idx = (long)blockIdx.x * blockDim.x + threadIdx.x; idx < total;
         idx += (long)gridDim.x * blockDim.x) {
        int e = (int)(idx / F);
        int f = (int)(idx - (long)e * F);
        int r = row[e], c = col[e];
        float w = dis[r] * dis[c];
        atomicAdd(&out[(size_t)c * F + f], H[(size_t)r * F + f] * w);
    }
}

// ---------------- bias + relu (in place), F=128 ----------------
__global__ void relu_bias_kernel(float* __restrict__ g, const float* __restrict__ b, long total) {
    for (long idx = (long)blockIdx.x * blockDim.x + threadIdx.x; idx < total;
         idx += (long)gridDim.x * blockDim.x) {
        int f = (int)(idx & 127);
        g[idx] = fmaxf(g[idx] + b[f], 0.0f);
    }
}

// ---------------- final: z = g2 + b2; out = log_softmax(z) ; one wave per node ----------------
__global__ void logsoftmax_kernel(const float* __restrict__ G, const float* __restrict__ b,
                                  float* __restrict__ out, int N) {
    int gtid = blockIdx.x * blockDim.x + threadIdx.x;
    int node = gtid >> 6;
    int lane = threadIdx.x & 63;
    if (node >= N) return;

    float v = (lane < 40) ? (G[(size_t)node * 40 + lane] + b[lane]) : -INFINITY;
    float m = v;
#pragma unroll
    for (int o = 32; o > 0; o >>= 1) m = fmaxf(m, __shfl_xor(m, o));
    float ex = (lane < 40) ? expf(v - m) : 0.0f;
    float s = ex;
#pragma unroll
    for (int o = 32; o > 0; o >>= 1) s += __shfl_xor(s, o);
    float ls = logf(s);
    if (lane < 40) out[(size_t)node * 40 + lane] = v - m - ls;
}

extern "C" void kernel_launch(void* const* d_in, const int* in_sizes, int n_in,
                              void* d_out, int out_size, void* d_ws, size_t ws_size,
                              hipStream_t stream) {
    const float* x  = (const float*)d_in[0];
    const int*   ei = (const int*)d_in[1];
    const float* W1 = (const float*)d_in[2];
    const float* b1 = (const float*)d_in[3];
    const float* W2 = (const float*)d_in[4];
    const float* b2 = (const float*)d_in[5];
    float* out = (float*)d_out;

    const int N = in_sizes[0] / 128;
    const int E = in_sizes[1] / 2;
    const int* row = ei;
    const int* col = ei + E;

    float* ws = (float*)d_ws;
    size_t disPad = ((size_t)N + 127) & ~(size_t)127;
    float* dis = ws;
    float* h1  = ws + disPad;                 // N*128
    float* g1  = h1 + (size_t)N * 128;        // N*128
    // after agg1, h1 region is dead: overlay h2/g2 there
    float* h2  = h1;                          // N*40
    float* g2  = h1 + (size_t)N * 40;         // N*40

    // 1) degrees -> dis
    init_deg_kernel<<<(N + 255) / 256, 256, 0, stream>>>(dis, N);
    accum_deg_kernel<<<(E + 255) / 256, 256, 0, stream>>>(col, dis, E);
    to_dis_kernel<<<(N + 255) / 256, 256, 0, stream>>>(dis, N);

    // 2) h1 = x @ W1
    gemm_kernel<128, 128, 32><<<(N + 31) / 32, 256, 0, stream>>>(x, W1, h1, N);

    // 3) g1 = A_norm @ h1
    {
        long total = (long)N * 128;
        int blocks = (int)min((total + 255) / 256, (long)65536);
        init_self_kernel<128><<<blocks, 256, 0, stream>>>(h1, dis, g1, N);
        long etotal = (long)E * 128;
        int eblocks = (int)min((etotal + 255) / 256, (long)65536);
        agg_kernel<128><<<eblocks, 256, 0, stream>>>(h1, row, col, dis, g1, E);
        // 4) a1 = relu(g1 + b1), in place
        relu_bias_kernel<<<blocks, 256, 0, stream>>>(g1, b1, total);
    }

    // 5) h2 = a1 @ W2
    gemm_kernel<40, 64, 32><<<(N + 31) / 32, 256, 0, stream>>>(g1, W2, h2, N);

    // 6) g2 = A_norm @ h2
    {
        long total = (long)N * 40;
        int blocks = (int)min((total + 255) / 256, (long)65536);
        init_self_kernel<40><<<blocks, 256, 0, stream>>>(h2, dis, g2, N);
        long etotal = (long)E * 40;
        int eblocks = (int)min((etotal + 255) / 256, (long)65536);
        agg_kernel<40><<<eblocks, 256, 0, stream>>>(h2, row, col, dis, g2, E);
    }

    // 7) out = log_softmax(g2 + b2)
    {
        long threads = (long)N * 64;
        int blocks = (int)((threads + 255) / 256);
        logsoftmax_kernel<<<blocks, 256, 0, stream>>>(g2, b2, out, N);
    }
}

// Round 2
// 655.650 us; speedup vs baseline: 1.8296x; 1.8296x over previous
//
#include <hip/hip_runtime.h>
#include <hip/hip_bf16.h>
#include <math.h>

#define SCAN_B 512

// ---------------- degree count (int) ----------------
__global__ void count_deg_kernel(const int* __restrict__ col, int* __restrict__ cnt, int E) {
    int e = blockIdx.x * blockDim.x + threadIdx.x;
    if (e < E) atomicAdd(&cnt[col[e]], 1);
}

__global__ void dis_kernel(const int* __restrict__ cnt, float* __restrict__ dis, int N) {
    int i = blockIdx.x * blockDim.x + threadIdx.x;
    if (i < N) dis[i] = rsqrtf((float)cnt[i] + 1.0f);  // +1 self-loop
}

// ---------------- exclusive scan (3 kernels) ----------------
__global__ void scan1_kernel(const int* __restrict__ cnt, int* __restrict__ offs,
                             int* __restrict__ blockSum, int N) {
    __shared__ int s[SCAN_B];
    int tid = threadIdx.x;
    int gi = blockIdx.x * SCAN_B + tid;
    int v = (gi < N) ? cnt[gi] : 0;
    s[tid] = v;
    __syncthreads();
    for (int off = 1; off < SCAN_B; off <<= 1) {
        int t = (tid >= off) ? s[tid - off] : 0;
        __syncthreads();
        s[tid] += t;
        __syncthreads();
    }
    if (gi < N) offs[gi] = s[tid] - v;  // exclusive within block
    if (tid == SCAN_B - 1) blockSum[blockIdx.x] = s[tid];
}

__global__ void scan2_kernel(int* __restrict__ blockSum, int nb) {
    __shared__ int s[SCAN_B];
    int tid = threadIdx.x;
    int v = (tid < nb) ? blockSum[tid] : 0;
    s[tid] = v;
    __syncthreads();
    for (int off = 1; off < SCAN_B; off <<= 1) {
        int t = (tid >= off) ? s[tid - off] : 0;
        __syncthreads();
        s[tid] += t;
        __syncthreads();
    }
    if (tid < nb) blockSum[tid] = s[tid] - v;  // exclusive, in place
}

__global__ void scan3_kernel(int* __restrict__ offs, const int* __restrict__ blockSum,
                             int* __restrict__ cursor, int N) {
    int i = blockIdx.x * blockDim.x + threadIdx.x;
    if (i < N) {
        int o = offs[i] + blockSum[i >> 9];
        offs[i] = o;
        cursor[i] = o;
    }
}

// ---------------- CSR fill ----------------
__global__ void fill_kernel(const int* __restrict__ row, const int* __restrict__ col,
                            int* __restrict__ cursor, int* __restrict__ csr, int E) {
    int e = blockIdx.x * blockDim.x + threadIdx.x;
    if (e < E) {
        int p = atomicAdd(&cursor[col[e]], 1);
        csr[p] = row[e];
    }
}

// ---------------- gather-aggregate on x (F=128), one wave per node ----------------
// xa[c] = dis[c] * ( sum_s dis[s]*x[s] + dis[c]*x[c] )
__global__ void gather1_kernel(const float* __restrict__ x, const int* __restrict__ offs,
                               const int* __restrict__ cnt, const int* __restrict__ csr,
                               const float* __restrict__ dis, float* __restrict__ xa, int N) {
    int node = blockIdx.x * 4 + (threadIdx.x >> 6);
    int lane = threadIdx.x & 63;
    if (node >= N) return;
    int off = offs[node], dg = cnt[node];
    const float2* X2 = (const float2*)x;
    float ax = 0.f, ay = 0.f;
    int s = (dg > 0) ? csr[off] : 0;
    for (int j = 0; j < dg; j++) {
        int sn = (j + 1 < dg) ? csr[off + j + 1] : 0;  // prefetch next index
        float w = dis[s];
        float2 v = X2[(size_t)s * 64 + lane];
        ax += v.x * w;
        ay += v.y * w;
        s = sn;
    }
    float dc = dis[node];
    float2 xv = X2[(size_t)node * 64 + lane];
    float2 o;
    o.x = dc * (ax + dc * xv.x);
    o.y = dc * (ay + dc * xv.y);
    ((float2*)xa)[(size_t)node * 64 + lane] = o;
}

// ---------------- GEMM1 in-place: A[32 rows] = relu(A @ W + b), K=M=128 ----------------
// 256 threads: 8 rowgroups x 32 colgroups, each thread 4 rows x 4 cols.
__global__ void gemm1_kernel(float* __restrict__ A, const float* __restrict__ W,
                             const float* __restrict__ bias, int N) {
    __shared__ float Xs[32][129];  // +1 pad: kills 8-way bank conflict on column reads
    int tid = threadIdx.x;
    int n0 = blockIdx.x * 32;
    for (int i = tid; i < 32 * 128; i += 256) {
        int r = i >> 7, k = i & 127;
        Xs[r][k] = A[(size_t)(n0 + r) * 128 + k];
    }
    __syncthreads();

    int colg = tid & 31, rowg = tid >> 5;
    const float4* W4 = (const float4*)W;
    float4 bb = ((const float4*)bias)[colg];
    float acc[4][4] = {};
#pragma unroll 4
    for (int k = 0; k < 128; k++) {
        float4 w = W4[k * 32 + colg];
        float x0 = Xs[rowg * 4 + 0][k];
        float x1 = Xs[rowg * 4 + 1][k];
        float x2 = Xs[rowg * 4 + 2][k];
        float x3 = Xs[rowg * 4 + 3][k];
        acc[0][0] += x0 * w.x; acc[0][1] += x0 * w.y; acc[0][2] += x0 * w.z; acc[0][3] += x0 * w.w;
        acc[1][0] += x1 * w.x; acc[1][1] += x1 * w.y; acc[1][2] += x1 * w.z; acc[1][3] += x1 * w.w;
        acc[2][0] += x2 * w.x; acc[2][1] += x2 * w.y; acc[2][2] += x2 * w.z; acc[2][3] += x2 * w.w;
        acc[3][0] += x3 * w.x; acc[3][1] += x3 * w.y; acc[3][2] += x3 * w.z; acc[3][3] += x3 * w.w;
    }
#pragma unroll
    for (int r = 0; r < 4; r++) {
        int n = n0 + rowg * 4 + r;
        float4 o;
        o.x = fmaxf(acc[r][0] + bb.x, 0.f);
        o.y = fmaxf(acc[r][1] + bb.y, 0.f);
        o.z = fmaxf(acc[r][2] + bb.z, 0.f);
        o.w = fmaxf(acc[r][3] + bb.w, 0.f);
        ((float4*)A)[(size_t)n * 32 + colg] = o;
    }
}

// ---------------- GEMM2: H[n][m] = sum_k A[n][k]*W[k][m], M=40, K=128 ----------------
template<int M, int MP, int BN>
__global__ void gemm_kernel(const float* __restrict__ X, const float* __restrict__ W,
                            float* __restrict__ H, int N) {
    __shared__ float Xs[BN][128];
    const int nThreads = 256;
    int n0 = blockIdx.x * BN;
    int tid = threadIdx.x;

    for (int i = tid; i < BN * 128; i += nThreads) {
        int r = i >> 7, k = i & 127;
        int n = n0 + r;
        Xs[r][k] = (n < N) ? X[(size_t)n * 128 + k] : 0.0f;
    }
    __syncthreads();

    int m = tid % MP;
    int r0 = tid / MP;
    constexpr int RSTRIDE = nThreads / MP;
    constexpr int RPT = BN / RSTRIDE;

    if (m < M) {
        float acc[RPT];
#pragma unroll
        for (int i = 0; i < RPT; i++) acc[i] = 0.0f;
        for (int k = 0; k < 128; k++) {
            float wk = W[(size_t)k * M + m];
#pragma unroll
            for (int i = 0; i < RPT; i++)
                acc[i] += Xs[r0 + i * RSTRIDE][k] * wk;
        }
#pragma unroll
        for (int i = 0; i < RPT; i++) {
            int n = n0 + r0 + i * RSTRIDE;
            if (n < N) H[(size_t)n * M + m] = acc[i];
        }
    }
}

// ---------------- gather-aggregate (F=40) + bias + log-softmax, one wave per node ----------------
__global__ void gather2_kernel(const float* __restrict__ h2, const int* __restrict__ offs,
                               const int* __restrict__ cnt, const int* __restrict__ csr,
                               const float* __restrict__ dis, const float* __restrict__ b2,
                               float* __restrict__ out, int N) {
    int node = blockIdx.x * 4 + (threadIdx.x >> 6);
    int lane = threadIdx.x & 63;
    if (node >= N) return;
    int off = offs[node], dg = cnt[node];
    float acc = 0.f;
    int s = (dg > 0) ? csr[off] : 0;
    for (int j = 0; j < dg; j++) {
        int sn = (j + 1 < dg) ? csr[off + j + 1] : 0;
        float w = dis[s];
        if (lane < 40) acc += h2[(size_t)s * 40 + lane] * w;
        s = sn;
    }
    float dc = dis[node];
    float v = -INFINITY;
    if (lane < 40) v = dc * (acc + dc * h2[(size_t)node * 40 + lane]) + b2[lane];
    float m = v;
#pragma unroll
    for (int o = 32; o > 0; o >>= 1) m = fmaxf(m, __shfl_xor(m, o));
    float ex = (lane < 40) ? expf(v - m) : 0.f;
    float sum = ex;
#pragma unroll
    for (int o = 32; o > 0; o >>= 1) sum += __shfl_xor(sum, o);
    float ls = logf(sum);
    if (lane < 40) out[(size_t)node * 40 + lane] = v - m - ls;
}

extern "C" void kernel_launch(void* const* d_in, const int* in_sizes, int n_in,
                              void* d_out, int out_size, void* d_ws, size_t ws_size,
                              hipStream_t stream) {
    const float* x  = (const float*)d_in[0];
    const int*   ei = (const int*)d_in[1];
    const float* W1 = (const float*)d_in[2];
    const float* b1 = (const float*)d_in[3];
    const float* W2 = (const float*)d_in[4];
    const float* b2 = (const float*)d_in[5];
    float* out = (float*)d_out;

    const int N = in_sizes[0] / 128;
    const int E = in_sizes[1] / 2;
    const int* row = ei;
    const int* col = ei + E;

    const int Npad = (N + 511) & ~511;
    const int Epad = (E + 511) & ~511;
    const int nb = (N + SCAN_B - 1) / SCAN_B;

    int* cnt      = (int*)d_ws;           // Npad
    int* offs     = cnt + Npad;           // Npad
    int* cursor   = offs + Npad;          // Npad
    int* blockSum = cursor + Npad;        // 512
    int* csr      = blockSum + 512;       // Epad
    float* dis    = (float*)(csr + Epad); // Npad
    float* xa     = dis + Npad;           // N*128 (in-place gemm1 -> a1)
    float* h2     = xa + (size_t)N * 128; // N*40

    // 1) degrees
    hipMemsetAsync(cnt, 0, (size_t)N * sizeof(int), stream);
    count_deg_kernel<<<(E + 255) / 256, 256, 0, stream>>>(col, cnt, E);
    dis_kernel<<<(N + 255) / 256, 256, 0, stream>>>(cnt, dis, N);

    // 2) CSR by destination
    scan1_kernel<<<nb, SCAN_B, 0, stream>>>(cnt, offs, blockSum, N);
    scan2_kernel<<<1, SCAN_B, 0, stream>>>(blockSum, nb);
    scan3_kernel<<<(N + 255) / 256, 256, 0, stream>>>(offs, blockSum, cursor, N);
    fill_kernel<<<(E + 255) / 256, 256, 0, stream>>>(row, col, cursor, csr, E);

    // 3) xa = A_norm @ x   (aggregation commuted before the GEMM)
    gather1_kernel<<<(N + 3) / 4, 256, 0, stream>>>(x, offs, cnt, csr, dis, xa, N);

    // 4) a1 = relu(xa @ W1 + b1), in place (each block owns its 32 rows)
    gemm1_kernel<<<N / 32, 256, 0, stream>>>(xa, W1, b1, N);

    // 5) h2 = a1 @ W2
    gemm_kernel<40, 64, 32><<<(N + 31) / 32, 256, 0, stream>>>(xa, W2, h2, N);

    // 6) out = log_softmax(A_norm @ h2 + b2)
    gather2_kernel<<<(N + 3) / 4, 256, 0, stream>>>(h2, offs, cnt, csr, dis, b2, out, N);
}

// Round 4
// 442.939 us; speedup vs baseline: 2.7082x; 1.4802x over previous
//
#include <hip/hip_runtime.h>
#include <hip/hip_bf16.h>
#include <math.h>

#define SCAN_B 512

typedef unsigned short u16x8 __attribute__((ext_vector_type(8)));

__device__ __forceinline__ float bf2f(unsigned int u) {
    union { unsigned int i; float f; } x;
    x.i = u << 16;
    return x.f;
}
__device__ __forceinline__ unsigned short f2bf(float f) {
    __hip_bfloat16 h = __float2bfloat16(f);
    return *reinterpret_cast<unsigned short*>(&h);
}

// ---------------- degree count (int) ----------------
__global__ void count_deg_kernel(const int* __restrict__ col, int* __restrict__ cnt, int E) {
    int e = blockIdx.x * blockDim.x + threadIdx.x;
    if (e < E) atomicAdd(&cnt[col[e]], 1);
}

__global__ void dis_kernel(const int* __restrict__ cnt, float* __restrict__ dis, int N) {
    int i = blockIdx.x * blockDim.x + threadIdx.x;
    if (i < N) dis[i] = rsqrtf((float)cnt[i] + 1.0f);  // +1 self-loop
}

// ---------------- exclusive scan (3 kernels) ----------------
__global__ void scan1_kernel(const int* __restrict__ cnt, int* __restrict__ offs,
                             int* __restrict__ blockSum, int N) {
    __shared__ int s[SCAN_B];
    int tid = threadIdx.x;
    int gi = blockIdx.x * SCAN_B + tid;
    int v = (gi < N) ? cnt[gi] : 0;
    s[tid] = v;
    __syncthreads();
    for (int off = 1; off < SCAN_B; off <<= 1) {
        int t = (tid >= off) ? s[tid - off] : 0;
        __syncthreads();
        s[tid] += t;
        __syncthreads();
    }
    if (gi < N) offs[gi] = s[tid] - v;
    if (tid == SCAN_B - 1) blockSum[blockIdx.x] = s[tid];
}

__global__ void scan2_kernel(int* __restrict__ blockSum, int nb) {
    __shared__ int s[SCAN_B];
    int tid = threadIdx.x;
    int v = (tid < nb) ? blockSum[tid] : 0;
    s[tid] = v;
    __syncthreads();
    for (int off = 1; off < SCAN_B; off <<= 1) {
        int t = (tid >= off) ? s[tid - off] : 0;
        __syncthreads();
        s[tid] += t;
        __syncthreads();
    }
    if (tid < nb) blockSum[tid] = s[tid] - v;
}

__global__ void scan3_kernel(int* __restrict__ offs, const int* __restrict__ blockSum,
                             int* __restrict__ cursor, int N) {
    int i = blockIdx.x * blockDim.x + threadIdx.x;
    if (i < N) {
        int o = offs[i] + blockSum[i >> 9];
        offs[i] = o;
        cursor[i] = o;
    }
}

// ---------------- CSR fill ----------------
__global__ void fill_kernel(const int* __restrict__ row, const int* __restrict__ col,
                            int* __restrict__ cursor, int* __restrict__ csr, int E) {
    int e = blockIdx.x * blockDim.x + threadIdx.x;
    if (e < E) {
        int p = atomicAdd(&cursor[col[e]], 1);
        csr[p] = row[e];
    }
}

// ---------------- x (f32) -> xb (bf16) ----------------
__global__ void cvt_kernel(const float* __restrict__ x, unsigned short* __restrict__ xb, long total8) {
    long i = (long)blockIdx.x * blockDim.x + threadIdx.x;
    if (i >= total8) return;
    float4 a = ((const float4*)x)[2 * i];
    float4 b = ((const float4*)x)[2 * i + 1];
    u16x8 o;
    o[0] = f2bf(a.x); o[1] = f2bf(a.y); o[2] = f2bf(a.z); o[3] = f2bf(a.w);
    o[4] = f2bf(b.x); o[5] = f2bf(b.y); o[6] = f2bf(b.z); o[7] = f2bf(b.w);
    ((u16x8*)xb)[i] = o;
}

// ---------------- gather1 (F=128 bf16): 4 edges in flight per wave ----------------
// xa[c] = dis[c] * ( sum_s dis[s]*xb[s] + dis[c]*xb[c] )
__global__ void gather1_kernel(const unsigned short* __restrict__ xb, const int* __restrict__ offs,
                               const int* __restrict__ cnt, const int* __restrict__ csr,
                               const float* __restrict__ dis, unsigned short* __restrict__ xa, int N) {
    int node = blockIdx.x * 4 + (threadIdx.x >> 6);
    int lane = threadIdx.x & 63;
    if (node >= N) return;
    int off = offs[node], dg = cnt[node];
    int g = lane >> 4, c = lane & 15;
    const u16x8* XB = (const u16x8*)xb;
    float acc[8] = {};
    int s = (g < dg) ? csr[off + g] : 0;
    for (int j = 0; j < dg; j += 4) {
        int jn = j + 4 + g;
        int sn = (jn < dg) ? csr[off + jn] : 0;
        float w = (j + g < dg) ? dis[s] : 0.f;
        u16x8 v = XB[(size_t)s * 16 + c];
#pragma unroll
        for (int k = 0; k < 8; k++) acc[k] += bf2f(v[k]) * w;
        s = sn;
    }
#pragma unroll
    for (int k = 0; k < 8; k++) {
        acc[k] += __shfl_xor(acc[k], 16);
        acc[k] += __shfl_xor(acc[k], 32);
    }
    float dc = dis[node];
    u16x8 xv = XB[(size_t)node * 16 + c];
    if (lane < 16) {
        u16x8 o;
#pragma unroll
        for (int k = 0; k < 8; k++) o[k] = f2bf(dc * (acc[k] + dc * bf2f(xv[k])));
        ((u16x8*)xa)[(size_t)node * 16 + c] = o;
    }
}

// ---------------- GEMM1 in-place (bf16 in/out, f32 VALU): A = relu(A@W1+b1) ----------------
__global__ void gemm1_kernel(unsigned short* __restrict__ A, const float* __restrict__ W,
                             const float* __restrict__ bias, int N) {
    __shared__ float Xs[32][128];
    int tid = threadIdx.x;
    int n0 = blockIdx.x * 32;
    for (int i = tid; i < 32 * 32; i += 256) {
        int r = i >> 5, k4 = i & 31;
        ushort4 v = ((const ushort4*)A)[(size_t)(n0 + r) * 32 + k4];
        Xs[r][k4 * 4 + 0] = bf2f(v.x);
        Xs[r][k4 * 4 + 1] = bf2f(v.y);
        Xs[r][k4 * 4 + 2] = bf2f(v.z);
        Xs[r][k4 * 4 + 3] = bf2f(v.w);
    }
    __syncthreads();

    int colg = tid & 31, rowg = tid >> 5;
    const float4* W4 = (const float4*)W;
    float4 bb = ((const float4*)bias)[colg];
    float acc[4][4] = {};
#pragma unroll 4
    for (int k = 0; k < 128; k++) {
        float4 w = W4[k * 32 + colg];
        float x0 = Xs[rowg * 4 + 0][k];
        float x1 = Xs[rowg * 4 + 1][k];
        float x2 = Xs[rowg * 4 + 2][k];
        float x3 = Xs[rowg * 4 + 3][k];
        acc[0][0] += x0 * w.x; acc[0][1] += x0 * w.y; acc[0][2] += x0 * w.z; acc[0][3] += x0 * w.w;
        acc[1][0] += x1 * w.x; acc[1][1] += x1 * w.y; acc[1][2] += x1 * w.z; acc[1][3] += x1 * w.w;
        acc[2][0] += x2 * w.x; acc[2][1] += x2 * w.y; acc[2][2] += x2 * w.z; acc[2][3] += x2 * w.w;
        acc[3][0] += x3 * w.x; acc[3][1] += x3 * w.y; acc[3][2] += x3 * w.z; acc[3][3] += x3 * w.w;
    }
#pragma unroll
    for (int r = 0; r < 4; r++) {
        int n = n0 + rowg * 4 + r;
        ushort4 o;
        o.x = f2bf(fmaxf(acc[r][0] + bb.x, 0.f));
        o.y = f2bf(fmaxf(acc[r][1] + bb.y, 0.f));
        o.z = f2bf(fmaxf(acc[r][2] + bb.z, 0.f));
        o.w = f2bf(fmaxf(acc[r][3] + bb.w, 0.f));
        ((ushort4*)A)[(size_t)n * 32 + colg] = o;
    }
}

// ---------------- GEMM2 (bf16 in, bf16 out padded to 64): h2 = a1 @ W2 ----------------
__global__ void gemm2_kernel(const unsigned short* __restrict__ A, const float* __restrict__ W,
                             unsigned short* __restrict__ H, int N) {
    __shared__ float Xs[32][128];
    int tid = threadIdx.x;
    int n0 = blockIdx.x * 32;
    for (int i = tid; i < 32 * 32; i += 256) {
        int r = i >> 5, k4 = i & 31;
        ushort4 v = ((const ushort4*)A)[(size_t)(n0 + r) * 32 + k4];
        Xs[r][k4 * 4 + 0] = bf2f(v.x);
        Xs[r][k4 * 4 + 1] = bf2f(v.y);
        Xs[r][k4 * 4 + 2] = bf2f(v.z);
        Xs[r][k4 * 4 + 3] = bf2f(v.w);
    }
    __syncthreads();

    int m = tid & 63, r0 = tid >> 6;
    if (m < 40) {
        float acc[8] = {};
        for (int k = 0; k < 128; k++) {
            float wk = W[(size_t)k * 40 + m];
#pragma unroll
            for (int i = 0; i < 8; i++) acc[i] += Xs[r0 + i * 4][k] * wk;
        }
#pragma unroll
        for (int i = 0; i < 8; i++) {
            int n = n0 + r0 + i * 4;
            if (n < N) H[(size_t)n * 64 + m] = f2bf(acc[i]);
        }
    }
}

// ---------------- gather2 (F=40 bf16 pad 64) + bias + log-softmax ----------------
__global__ void gather2_kernel(const unsigned short* __restrict__ h2, const int* __restrict__ offs,
                               const int* __restrict__ cnt, const int* __restrict__ csr,
                               const float* __restrict__ dis, const float* __restrict__ b2,
                               float* __restrict__ out, int N) {
    int node = blockIdx.x * 4 + (threadIdx.x >> 6);
    int lane = threadIdx.x & 63;
    if (node >= N) return;
    int off = offs[node], dg = cnt[node];
    int g = lane >> 5, c = lane & 31;
    bool act = c < 20;
    float a0 = 0.f, a1 = 0.f;
    int s = (g < dg) ? csr[off + g] : 0;
    for (int j = 0; j < dg; j += 2) {
        int jn = j + 2 + g;
        int sn = (jn < dg) ? csr[off + jn] : 0;
        float w = (j + g < dg) ? dis[s] : 0.f;
        if (act) {
            unsigned int u = ((const unsigned int*)(h2 + (size_t)s * 64))[c];
            a0 += bf2f(u & 0xffffu) * w;
            a1 += bf2f(u >> 16) * w;
        }
        s = sn;
    }
    a0 += __shfl_xor(a0, 32);
    a1 += __shfl_xor(a1, 32);
    float dc = dis[node];
    float v0 = -INFINITY, v1 = -INFINITY;
    if (act) {
        unsigned int u = ((const unsigned int*)(h2 + (size_t)node * 64))[c];
        v0 = dc * (a0 + dc * bf2f(u & 0xffffu)) + b2[2 * c];
        v1 = dc * (a1 + dc * bf2f(u >> 16)) + b2[2 * c + 1];
    }
    float m = fmaxf(v0, v1);
#pragma unroll
    for (int o = 32; o > 0; o >>= 1) m = fmaxf(m, __shfl_xor(m, o));
    // both g-halves hold identical v0/v1 after the fold above, so the full
    // 64-lane butterfly double-counts the denominator -> scale by 0.5
    float ex = act ? (__expf(v0 - m) + __expf(v1 - m)) : 0.f;
#pragma unroll
    for (int o = 32; o > 0; o >>= 1) ex += __shfl_xor(ex, o);
    float ls = __logf(0.5f * ex);
    if (lane < 20) {
        float2 o2 = make_float2(v0 - m - ls, v1 - m - ls);
        ((float2*)(out + (size_t)node * 40))[c] = o2;
    }
}

extern "C" void kernel_launch(void* const* d_in, const int* in_sizes, int n_in,
                              void* d_out, int out_size, void* d_ws, size_t ws_size,
                              hipStream_t stream) {
    const float* x  = (const float*)d_in[0];
    const int*   ei = (const int*)d_in[1];
    const float* W1 = (const float*)d_in[2];
    const float* b1 = (const float*)d_in[3];
    const float* W2 = (const float*)d_in[4];
    const float* b2 = (const float*)d_in[5];
    float* out = (float*)d_out;

    const int N = in_sizes[0] / 128;
    const int E = in_sizes[1] / 2;
    const int* row = ei;
    const int* col = ei + E;

    const int Npad = (N + 511) & ~511;
    const int Epad = (E + 511) & ~511;
    const int nb = (N + SCAN_B - 1) / SCAN_B;

    int* cnt      = (int*)d_ws;           // Npad
    int* offs     = cnt + Npad;           // Npad
    int* cursor   = offs + Npad;          // Npad
    int* blockSum = cursor + Npad;        // 512
    int* csr      = blockSum + 512;       // Epad
    float* dis    = (float*)(csr + Epad); // Npad
    unsigned short* xb = (unsigned short*)(dis + Npad);   // N*128 bf16
    unsigned short* xa = xb + (size_t)N * 128;            // N*128 bf16 (in-place a1)
    unsigned short* h2 = xa + (size_t)N * 128;            // N*64 bf16 (40 used)

    // 1) degrees
    hipMemsetAsync(cnt, 0, (size_t)N * sizeof(int), stream);
    count_deg_kernel<<<(E + 255) / 256, 256, 0, stream>>>(col, cnt, E);
    dis_kernel<<<(N + 255) / 256, 256, 0, stream>>>(cnt, dis, N);

    // 2) CSR by destination
    scan1_kernel<<<nb, SCAN_B, 0, stream>>>(cnt, offs, blockSum, N);
    scan2_kernel<<<1, SCAN_B, 0, stream>>>(blockSum, nb);
    scan3_kernel<<<(N + 255) / 256, 256, 0, stream>>>(offs, blockSum, cursor, N);
    fill_kernel<<<(E + 255) / 256, 256, 0, stream>>>(row, col, cursor, csr, E);

    // 3) xb = bf16(x)
    {
        long total8 = (long)N * 16;  // N*128/8
        cvt_kernel<<<(int)((total8 + 255) / 256), 256, 0, stream>>>(x, xb, total8);
    }

    // 4) xa = A_norm @ xb
    gather1_kernel<<<(N + 3) / 4, 256, 0, stream>>>(xb, offs, cnt, csr, dis, xa, N);

    // 5) a1 = relu(xa @ W1 + b1), in place
    gemm1_kernel<<<N / 32, 256, 0, stream>>>(xa, W1, b1, N);

    // 6) h2 = a1 @ W2 (padded to 64 cols)
    gemm2_kernel<<<(N + 31) / 32, 256, 0, stream>>>(xa, W2, h2, N);

    // 7) out = log_softmax(A_norm @ h2 + b2)
    gather2_kernel<<<(N + 3) / 4, 256, 0, stream>>>(h2, offs, cnt, csr, dis, b2, out, N);
}

// Round 5
// 382.295 us; speedup vs baseline: 3.1378x; 1.1586x over previous
//
#include <hip/hip_runtime.h>
#include <hip/hip_bf16.h>
#include <math.h>

#define SCAN_B 512

typedef unsigned short u16x8 __attribute__((ext_vector_type(8)));

__device__ __forceinline__ float bf2f(unsigned int u) {
    union { unsigned int i; float f; } x;
    x.i = u << 16;
    return x.f;
}
__device__ __forceinline__ unsigned short f2bf(float f) {
    __hip_bfloat16 h = __float2bfloat16(f);
    return *reinterpret_cast<unsigned short*>(&h);
}

// ---------------- degree count (int) ----------------
__global__ void count_deg_kernel(const int* __restrict__ col, int* __restrict__ cnt, int E) {
    int e = blockIdx.x * blockDim.x + threadIdx.x;
    if (e < E) atomicAdd(&cnt[col[e]], 1);
}

__global__ void dis_kernel(const int* __restrict__ cnt, float* __restrict__ dis, int N) {
    int i = blockIdx.x * blockDim.x + threadIdx.x;
    if (i < N) dis[i] = rsqrtf((float)cnt[i] + 1.0f);  // +1 self-loop
}

// ---------------- exclusive scan (3 kernels) ----------------
__global__ void scan1_kernel(const int* __restrict__ cnt, int* __restrict__ offs,
                             int* __restrict__ blockSum, int N) {
    __shared__ int s[SCAN_B];
    int tid = threadIdx.x;
    int gi = blockIdx.x * SCAN_B + tid;
    int v = (gi < N) ? cnt[gi] : 0;
    s[tid] = v;
    __syncthreads();
    for (int off = 1; off < SCAN_B; off <<= 1) {
        int t = (tid >= off) ? s[tid - off] : 0;
        __syncthreads();
        s[tid] += t;
        __syncthreads();
    }
    if (gi < N) offs[gi] = s[tid] - v;
    if (tid == SCAN_B - 1) blockSum[blockIdx.x] = s[tid];
}

__global__ void scan2_kernel(int* __restrict__ blockSum, int nb) {
    __shared__ int s[SCAN_B];
    int tid = threadIdx.x;
    int v = (tid < nb) ? blockSum[tid] : 0;
    s[tid] = v;
    __syncthreads();
    for (int off = 1; off < SCAN_B; off <<= 1) {
        int t = (tid >= off) ? s[tid - off] : 0;
        __syncthreads();
        s[tid] += t;
        __syncthreads();
    }
    if (tid < nb) blockSum[tid] = s[tid] - v;
}

// also initializes per-node cursor and per-bucket (col>>8) cursor
__global__ void scan3_kernel(int* __restrict__ offs, const int* __restrict__ blockSum,
                             int* __restrict__ cursor, int* __restrict__ bcur, int N) {
    int i = blockIdx.x * blockDim.x + threadIdx.x;
    if (i < N) {
        int o = offs[i] + blockSum[i >> 9];
        offs[i] = o;
        cursor[i] = o;
        if ((i & 255) == 0) bcur[i >> 8] = o;
    }
}

// ---------------- binned CSR build, pass 1: edges -> bucket-sorted tmp ----------------
// bucket b = col>>8; tmp entry = row | (col&255)<<20
#define BIN_TILE 4096
__global__ void bin_kernel(const int* __restrict__ row, const int* __restrict__ col,
                           int* __restrict__ bcur, unsigned* __restrict__ tmp, int E, int NB) {
    __shared__ unsigned hist[512];
    int tid = threadIdx.x;
    int base = blockIdx.x * BIN_TILE;
    for (int i = tid; i < NB; i += 256) hist[i] = 0;
    __syncthreads();
#pragma unroll
    for (int i = 0; i < BIN_TILE / 256; i++) {
        int e = base + tid + i * 256;
        if (e < E) atomicAdd(&hist[col[e] >> 8], 1u);
    }
    __syncthreads();
    for (int i = tid; i < NB; i += 256) {
        unsigned h = hist[i];
        hist[i] = h ? (unsigned)atomicAdd(&bcur[i], (int)h) : 0u;
    }
    __syncthreads();
#pragma unroll
    for (int i = 0; i < BIN_TILE / 256; i++) {
        int e = base + tid + i * 256;
        if (e < E) {
            int c = col[e], r = row[e];
            unsigned p = atomicAdd(&hist[c >> 8], 1u);
            tmp[p] = (unsigned)r | ((unsigned)(c & 255) << 20);
        }
    }
}

// ---------------- binned CSR build, pass 2: one block per bucket, local fine scatter ----------------
__global__ void scatter_kernel(const unsigned* __restrict__ tmp, const int* __restrict__ offs,
                               int* __restrict__ cursor, int* __restrict__ csr, int E, int N) {
    int b = blockIdx.x;
    int start = offs[b << 8];
    int hi = (b + 1) << 8;
    int end = (hi < N) ? offs[hi] : E;
    for (int i = start + threadIdx.x; i < end; i += blockDim.x) {
        unsigned u = tmp[i];
        int r = (int)(u & 0xFFFFFu);
        int c = (b << 8) + (int)(u >> 20);
        int p = atomicAdd(&cursor[c], 1);
        csr[p] = r;
    }
}

// ---------------- x (f32) -> xb (bf16) ----------------
__global__ void cvt_kernel(const float* __restrict__ x, unsigned short* __restrict__ xb, long total8) {
    long i = (long)blockIdx.x * blockDim.x + threadIdx.x;
    if (i >= total8) return;
    float4 a = ((const float4*)x)[2 * i];
    float4 b = ((const float4*)x)[2 * i + 1];
    u16x8 o;
    o[0] = f2bf(a.x); o[1] = f2bf(a.y); o[2] = f2bf(a.z); o[3] = f2bf(a.w);
    o[4] = f2bf(b.x); o[5] = f2bf(b.y); o[6] = f2bf(b.z); o[7] = f2bf(b.w);
    ((u16x8*)xb)[i] = o;
}

// ---------------- gather1 (F=128 bf16): 8 edges in flight per wave ----------------
// xa[c] = dis[c] * ( sum_s dis[s]*xb[s] + dis[c]*xb[c] )
__global__ void gather1_kernel(const unsigned short* __restrict__ xb, const int* __restrict__ offs,
                               const int* __restrict__ cnt, const int* __restrict__ csr,
                               const float* __restrict__ dis, unsigned short* __restrict__ xa, int N) {
    int node = blockIdx.x * 4 + (threadIdx.x >> 6);
    int lane = threadIdx.x & 63;
    if (node >= N) return;
    int off = offs[node], dg = cnt[node];
    int g = lane >> 4, c = lane & 15;
    const u16x8* XB = (const u16x8*)xb;
    float acc[8] = {};
    int s0 = (g < dg) ? csr[off + g] : 0;
    int s1 = (g + 4 < dg) ? csr[off + g + 4] : 0;
    for (int j = 0; j < dg; j += 8) {
        int j2 = j + 8;
        int sn0 = (j2 + g < dg) ? csr[off + j2 + g] : 0;
        int sn1 = (j2 + 4 + g < dg) ? csr[off + j2 + 4 + g] : 0;
        float w0 = (j + g < dg) ? dis[s0] : 0.f;
        float w1 = (j + 4 + g < dg) ? dis[s1] : 0.f;
        u16x8 v0 = XB[(size_t)s0 * 16 + c];
        u16x8 v1 = XB[(size_t)s1 * 16 + c];
#pragma unroll
        for (int k = 0; k < 8; k++) acc[k] += bf2f(v0[k]) * w0 + bf2f(v1[k]) * w1;
        s0 = sn0; s1 = sn1;
    }
#pragma unroll
    for (int k = 0; k < 8; k++) {
        acc[k] += __shfl_xor(acc[k], 16);
        acc[k] += __shfl_xor(acc[k], 32);
    }
    float dc = dis[node];
    u16x8 xv = XB[(size_t)node * 16 + c];
    if (lane < 16) {
        u16x8 o;
#pragma unroll
        for (int k = 0; k < 8; k++) o[k] = f2bf(dc * (acc[k] + dc * bf2f(xv[k])));
        ((u16x8*)xa)[(size_t)node * 16 + c] = o;
    }
}

// ---------------- GEMM1 in-place (bf16 in/out, f32 VALU): A = relu(A@W1+b1) ----------------
__global__ void gemm1_kernel(unsigned short* __restrict__ A, const float* __restrict__ W,
                             const float* __restrict__ bias, int N) {
    __shared__ float Xs[32][128];
    int tid = threadIdx.x;
    int n0 = blockIdx.x * 32;
    for (int i = tid; i < 32 * 32; i += 256) {
        int r = i >> 5, k4 = i & 31;
        ushort4 v = ((const ushort4*)A)[(size_t)(n0 + r) * 32 + k4];
        Xs[r][k4 * 4 + 0] = bf2f(v.x);
        Xs[r][k4 * 4 + 1] = bf2f(v.y);
        Xs[r][k4 * 4 + 2] = bf2f(v.z);
        Xs[r][k4 * 4 + 3] = bf2f(v.w);
    }
    __syncthreads();

    int colg = tid & 31, rowg = tid >> 5;
    const float4* W4 = (const float4*)W;
    float4 bb = ((const float4*)bias)[colg];
    float acc[4][4] = {};
#pragma unroll 4
    for (int k = 0; k < 128; k++) {
        float4 w = W4[k * 32 + colg];
        float x0 = Xs[rowg * 4 + 0][k];
        float x1 = Xs[rowg * 4 + 1][k];
        float x2 = Xs[rowg * 4 + 2][k];
        float x3 = Xs[rowg * 4 + 3][k];
        acc[0][0] += x0 * w.x; acc[0][1] += x0 * w.y; acc[0][2] += x0 * w.z; acc[0][3] += x0 * w.w;
        acc[1][0] += x1 * w.x; acc[1][1] += x1 * w.y; acc[1][2] += x1 * w.z; acc[1][3] += x1 * w.w;
        acc[2][0] += x2 * w.x; acc[2][1] += x2 * w.y; acc[2][2] += x2 * w.z; acc[2][3] += x2 * w.w;
        acc[3][0] += x3 * w.x; acc[3][1] += x3 * w.y; acc[3][2] += x3 * w.z; acc[3][3] += x3 * w.w;
    }
#pragma unroll
    for (int r = 0; r < 4; r++) {
        int n = n0 + rowg * 4 + r;
        ushort4 o;
        o.x = f2bf(fmaxf(acc[r][0] + bb.x, 0.f));
        o.y = f2bf(fmaxf(acc[r][1] + bb.y, 0.f));
        o.z = f2bf(fmaxf(acc[r][2] + bb.z, 0.f));
        o.w = f2bf(fmaxf(acc[r][3] + bb.w, 0.f));
        ((ushort4*)A)[(size_t)n * 32 + colg] = o;
    }
}

// ---------------- GEMM2 (bf16 in, bf16 out padded to 64): h2 = a1 @ W2 ----------------
__global__ void gemm2_kernel(const unsigned short* __restrict__ A, const float* __restrict__ W,
                             unsigned short* __restrict__ H, int N) {
    __shared__ float Xs[32][128];
    int tid = threadIdx.x;
    int n0 = blockIdx.x * 32;
    for (int i = tid; i < 32 * 32; i += 256) {
        int r = i >> 5, k4 = i & 31;
        ushort4 v = ((const ushort4*)A)[(size_t)(n0 + r) * 32 + k4];
        Xs[r][k4 * 4 + 0] = bf2f(v.x);
        Xs[r][k4 * 4 + 1] = bf2f(v.y);
        Xs[r][k4 * 4 + 2] = bf2f(v.z);
        Xs[r][k4 * 4 + 3] = bf2f(v.w);
    }
    __syncthreads();

    int m = tid & 63, r0 = tid >> 6;
    if (m < 40) {
        float acc[8] = {};
        for (int k = 0; k < 128; k++) {
            float wk = W[(size_t)k * 40 + m];
#pragma unroll
            for (int i = 0; i < 8; i++) acc[i] += Xs[r0 + i * 4][k] * wk;
        }
#pragma unroll
        for (int i = 0; i < 8; i++) {
            int n = n0 + r0 + i * 4;
            if (n < N) H[(size_t)n * 64 + m] = f2bf(acc[i]);
        }
    }
}

// ---------------- gather2 (F=40 bf16 pad 64) + bias + log-softmax, 4 edges in flight ----------------
__global__ void gather2_kernel(const unsigned short* __restrict__ h2, const int* __restrict__ offs,
                               const int* __restrict__ cnt, const int* __restrict__ csr,
                               const float* __restrict__ dis, const float* __restrict__ b2,
                               float* __restrict__ out, int N) {
    int node = blockIdx.x * 4 + (threadIdx.x >> 6);
    int lane = threadIdx.x & 63;
    if (node >= N) return;
    int off = offs[node], dg = cnt[node];
    int g = lane >> 5, c = lane & 31;
    bool act = c < 20;
    float a0 = 0.f, a1 = 0.f;
    int s0 = (g < dg) ? csr[off + g] : 0;
    int s1 = (g + 2 < dg) ? csr[off + g + 2] : 0;
    for (int j = 0; j < dg; j += 4) {
        int j2 = j + 4;
        int sn0 = (j2 + g < dg) ? csr[off + j2 + g] : 0;
        int sn1 = (j2 + 2 + g < dg) ? csr[off + j2 + 2 + g] : 0;
        float w0 = (j + g < dg) ? dis[s0] : 0.f;
        float w1 = (j + 2 + g < dg) ? dis[s1] : 0.f;
        if (act) {
            unsigned int u0 = ((const unsigned int*)(h2 + (size_t)s0 * 64))[c];
            unsigned int u1 = ((const unsigned int*)(h2 + (size_t)s1 * 64))[c];
            a0 += bf2f(u0 & 0xffffu) * w0 + bf2f(u1 & 0xffffu) * w1;
            a1 += bf2f(u0 >> 16) * w0 + bf2f(u1 >> 16) * w1;
        }
        s0 = sn0; s1 = sn1;
    }
    a0 += __shfl_xor(a0, 32);
    a1 += __shfl_xor(a1, 32);
    float dc = dis[node];
    float v0 = -INFINITY, v1 = -INFINITY;
    if (act) {
        unsigned int u = ((const unsigned int*)(h2 + (size_t)node * 64))[c];
        v0 = dc * (a0 + dc * bf2f(u & 0xffffu)) + b2[2 * c];
        v1 = dc * (a1 + dc * bf2f(u >> 16)) + b2[2 * c + 1];
    }
    float m = fmaxf(v0, v1);
#pragma unroll
    for (int o = 32; o > 0; o >>= 1) m = fmaxf(m, __shfl_xor(m, o));
    // both g-halves hold identical v0/v1 after the fold above, so the full
    // 64-lane butterfly double-counts the denominator -> scale by 0.5
    float ex = act ? (__expf(v0 - m) + __expf(v1 - m)) : 0.f;
#pragma unroll
    for (int o = 32; o > 0; o >>= 1) ex += __shfl_xor(ex, o);
    float ls = __logf(0.5f * ex);
    if (lane < 20) {
        float2 o2 = make_float2(v0 - m - ls, v1 - m - ls);
        ((float2*)(out + (size_t)node * 40))[c] = o2;
    }
}

extern "C" void kernel_launch(void* const* d_in, const int* in_sizes, int n_in,
                              void* d_out, int out_size, void* d_ws, size_t ws_size,
                              hipStream_t stream) {
    const float* x  = (const float*)d_in[0];
    const int*   ei = (const int*)d_in[1];
    const float* W1 = (const float*)d_in[2];
    const float* b1 = (const float*)d_in[3];
    const float* W2 = (const float*)d_in[4];
    const float* b2 = (const float*)d_in[5];
    float* out = (float*)d_out;

    const int N = in_sizes[0] / 128;
    const int E = in_sizes[1] / 2;
    const int* row = ei;
    const int* col = ei + E;

    const int Npad = (N + 511) & ~511;
    const int Epad = (E + 511) & ~511;
    const int nb = (N + SCAN_B - 1) / SCAN_B;
    const int NB = (N + 255) >> 8;  // coarse buckets (col>>8); <=512 for N<=131072

    int* cnt      = (int*)d_ws;           // Npad
    int* offs     = cnt + Npad;           // Npad
    int* cursor   = offs + Npad;          // Npad
    int* blockSum = cursor + Npad;        // 512
    int* bcur     = blockSum + 512;       // 512
    int* csr      = bcur + 512;           // Epad
    unsigned* tmp = (unsigned*)(csr + Epad);              // Epad
    float* dis    = (float*)(tmp + Epad); // Npad
    unsigned short* xb = (unsigned short*)(dis + Npad);   // N*128 bf16
    unsigned short* xa = xb + (size_t)N * 128;            // N*128 bf16 (in-place a1)
    unsigned short* h2 = xa + (size_t)N * 128;            // N*64 bf16 (40 used)

    // 1) degrees
    hipMemsetAsync(cnt, 0, (size_t)N * sizeof(int), stream);
    count_deg_kernel<<<(E + 255) / 256, 256, 0, stream>>>(col, cnt, E);
    dis_kernel<<<(N + 255) / 256, 256, 0, stream>>>(cnt, dis, N);

    // 2) CSR by destination: scan + binned 2-pass counting sort
    scan1_kernel<<<nb, SCAN_B, 0, stream>>>(cnt, offs, blockSum, N);
    scan2_kernel<<<1, SCAN_B, 0, stream>>>(blockSum, nb);
    scan3_kernel<<<(N + 255) / 256, 256, 0, stream>>>(offs, blockSum, cursor, bcur, N);
    bin_kernel<<<(E + BIN_TILE - 1) / BIN_TILE, 256, 0, stream>>>(row, col, bcur, tmp, E, NB);
    scatter_kernel<<<NB, 256, 0, stream>>>(tmp, offs, cursor, csr, E, N);

    // 3) xb = bf16(x)
    {
        long total8 = (long)N * 16;  // N*128/8
        cvt_kernel<<<(int)((total8 + 255) / 256), 256, 0, stream>>>(x, xb, total8);
    }

    // 4) xa = A_norm @ xb
    gather1_kernel<<<(N + 3) / 4, 256, 0, stream>>>(xb, offs, cnt, csr, dis, xa, N);

    // 5) a1 = relu(xa @ W1 + b1), in place
    gemm1_kernel<<<N / 32, 256, 0, stream>>>(xa, W1, b1, N);

    // 6) h2 = a1 @ W2 (padded to 64 cols)
    gemm2_kernel<<<(N + 31) / 32, 256, 0, stream>>>(xa, W2, h2, N);

    // 7) out = log_softmax(A_norm @ h2 + b2)
    gather2_kernel<<<(N + 3) / 4, 256, 0, stream>>>(h2, offs, cnt, csr, dis, b2, out, N);
}

// Round 6
// 286.444 us; speedup vs baseline: 4.1878x; 1.3346x over previous
//
#include <hip/hip_runtime.h>
#include <hip/hip_bf16.h>
#include <math.h>

#define SCAN_B 512

typedef unsigned short u16x8 __attribute__((ext_vector_type(8)));
typedef short s16x8 __attribute__((ext_vector_type(8)));
typedef float f32x4 __attribute__((ext_vector_type(4)));

__device__ __forceinline__ float bf2f(unsigned int u) {
    union { unsigned int i; float f; } x;
    x.i = u << 16;
    return x.f;
}
__device__ __forceinline__ unsigned short f2bf(float f) {
    __hip_bfloat16 h = __float2bfloat16(f);
    return *reinterpret_cast<unsigned short*>(&h);
}

// ---------------- degree count (int) ----------------
__global__ void count_deg_kernel(const int* __restrict__ col, int* __restrict__ cnt, int E) {
    int e = blockIdx.x * blockDim.x + threadIdx.x;
    if (e < E) atomicAdd(&cnt[col[e]], 1);
}

__global__ void dis_kernel(const int* __restrict__ cnt, float* __restrict__ dis, int N) {
    int i = blockIdx.x * blockDim.x + threadIdx.x;
    if (i < N) dis[i] = rsqrtf((float)cnt[i] + 1.0f);  // +1 self-loop
}

// ---------------- exclusive scan (3 kernels) ----------------
__global__ void scan1_kernel(const int* __restrict__ cnt, int* __restrict__ offs,
                             int* __restrict__ blockSum, int N) {
    __shared__ int s[SCAN_B];
    int tid = threadIdx.x;
    int gi = blockIdx.x * SCAN_B + tid;
    int v = (gi < N) ? cnt[gi] : 0;
    s[tid] = v;
    __syncthreads();
    for (int off = 1; off < SCAN_B; off <<= 1) {
        int t = (tid >= off) ? s[tid - off] : 0;
        __syncthreads();
        s[tid] += t;
        __syncthreads();
    }
    if (gi < N) offs[gi] = s[tid] - v;
    if (tid == SCAN_B - 1) blockSum[blockIdx.x] = s[tid];
}

__global__ void scan2_kernel(int* __restrict__ blockSum, int nb) {
    __shared__ int s[SCAN_B];
    int tid = threadIdx.x;
    int v = (tid < nb) ? blockSum[tid] : 0;
    s[tid] = v;
    __syncthreads();
    for (int off = 1; off < SCAN_B; off <<= 1) {
        int t = (tid >= off) ? s[tid - off] : 0;
        __syncthreads();
        s[tid] += t;
        __syncthreads();
    }
    if (tid < nb) blockSum[tid] = s[tid] - v;
}

// also initializes per-node cursor and per-bucket (col>>8) cursor
__global__ void scan3_kernel(int* __restrict__ offs, const int* __restrict__ blockSum,
                             int* __restrict__ cursor, int* __restrict__ bcur, int N) {
    int i = blockIdx.x * blockDim.x + threadIdx.x;
    if (i < N) {
        int o = offs[i] + blockSum[i >> 9];
        offs[i] = o;
        cursor[i] = o;
        if ((i & 255) == 0) bcur[i >> 8] = o;
    }
}

// ---------------- binned CSR build, pass 1 ----------------
#define BIN_TILE 4096
__global__ void bin_kernel(const int* __restrict__ row, const int* __restrict__ col,
                           int* __restrict__ bcur, unsigned* __restrict__ tmp, int E, int NB) {
    __shared__ unsigned hist[512];
    int tid = threadIdx.x;
    int base = blockIdx.x * BIN_TILE;
    for (int i = tid; i < NB; i += 256) hist[i] = 0;
    __syncthreads();
#pragma unroll
    for (int i = 0; i < BIN_TILE / 256; i++) {
        int e = base + tid + i * 256;
        if (e < E) atomicAdd(&hist[col[e] >> 8], 1u);
    }
    __syncthreads();
    for (int i = tid; i < NB; i += 256) {
        unsigned h = hist[i];
        hist[i] = h ? (unsigned)atomicAdd(&bcur[i], (int)h) : 0u;
    }
    __syncthreads();
#pragma unroll
    for (int i = 0; i < BIN_TILE / 256; i++) {
        int e = base + tid + i * 256;
        if (e < E) {
            int c = col[e], r = row[e];
            unsigned p = atomicAdd(&hist[c >> 8], 1u);
            tmp[p] = (unsigned)r | ((unsigned)(c & 255) << 20);
        }
    }
}

// ---------------- binned CSR build, pass 2 ----------------
__global__ void scatter_kernel(const unsigned* __restrict__ tmp, const int* __restrict__ offs,
                               int* __restrict__ cursor, int* __restrict__ csr, int E, int N) {
    int b = blockIdx.x;
    int start = offs[b << 8];
    int hi = (b + 1) << 8;
    int end = (hi < N) ? offs[hi] : E;
    for (int i = start + threadIdx.x; i < end; i += blockDim.x) {
        unsigned u = tmp[i];
        int r = (int)(u & 0xFFFFFu);
        int c = (b << 8) + (int)(u >> 20);
        int p = atomicAdd(&cursor[c], 1);
        csr[p] = r;
    }
}

// ---------------- xbs[i] = bf16(dis[i]*x[i]); sentinel row N = 0 ----------------
__global__ void scale_cvt_kernel(const float* __restrict__ x, const float* __restrict__ dis,
                                 unsigned short* __restrict__ xbs, int N) {
    long idx = (long)blockIdx.x * blockDim.x + threadIdx.x;  // one u16x8 chunk
    long total8 = (long)(N + 1) * 16;
    if (idx >= total8) return;
    int i = (int)(idx >> 4);
    u16x8 o;
    if (i >= N) {
#pragma unroll
        for (int k = 0; k < 8; k++) o[k] = 0;
    } else {
        float d = dis[i];
        float4 a = ((const float4*)x)[2 * idx];
        float4 b = ((const float4*)x)[2 * idx + 1];
        o[0] = f2bf(d * a.x); o[1] = f2bf(d * a.y); o[2] = f2bf(d * a.z); o[3] = f2bf(d * a.w);
        o[4] = f2bf(d * b.x); o[5] = f2bf(d * b.y); o[6] = f2bf(d * b.z); o[7] = f2bf(d * b.w);
    }
    ((u16x8*)xbs)[idx] = o;
}

// ---------------- zero h2s sentinel row N ----------------
__global__ void zrow_kernel(unsigned* __restrict__ p32) {
    if (threadIdx.x < 32) p32[threadIdx.x] = 0;
}

// ---------------- W packs into MFMA B-fragment order ----------------
// frag fc=(ct*4+kc): lane l, j: B[k][n], n=ct*16+(l&15), k=kc*32+(l>>4)*8+j
__global__ void w1pack_kernel(const float* __restrict__ W, unsigned short* __restrict__ wp) {
    int t = blockIdx.x * blockDim.x + threadIdx.x;
    if (t >= 2048) return;
    int lane = t & 63, fc = t >> 6;
    int ct = fc >> 2, kc = fc & 3;
    int n = ct * 16 + (lane & 15);
    int k0 = kc * 32 + (lane >> 4) * 8;
    u16x8 o;
#pragma unroll
    for (int j = 0; j < 8; j++) o[j] = f2bf(W[(size_t)(k0 + j) * 128 + n]);
    ((u16x8*)wp)[t] = o;
}

__global__ void w2pack_kernel(const float* __restrict__ W, unsigned short* __restrict__ wp) {
    int t = blockIdx.x * blockDim.x + threadIdx.x;
    if (t >= 768) return;
    int lane = t & 63, fc = t >> 6;
    int ct = fc >> 2, kc = fc & 3;
    int n = ct * 16 + (lane & 15);
    int k0 = kc * 32 + (lane >> 4) * 8;
    u16x8 o;
#pragma unroll
    for (int j = 0; j < 8; j++) o[j] = (n < 40) ? f2bf(W[(size_t)(k0 + j) * 40 + n]) : (unsigned short)0;
    ((u16x8*)wp)[t] = o;
}

// ---------------- gather1: xa[c] = dc * ( sum_s xbs[s] + xbs[c] ), 8 edges in flight ----------------
__global__ void gather1_kernel(const unsigned short* __restrict__ xbs, const int* __restrict__ offs,
                               const int* __restrict__ cnt, const int* __restrict__ csr,
                               const float* __restrict__ dis, unsigned short* __restrict__ xa, int N) {
    int node = blockIdx.x * 4 + (threadIdx.x >> 6);
    int lane = threadIdx.x & 63;
    if (node >= N) return;
    int off = offs[node], dg = cnt[node];
    int g = lane >> 4, c = lane & 15;
    const u16x8* XB = (const u16x8*)xbs;
    float acc[8] = {};
    int s0 = (g < dg) ? csr[off + g] : N;
    int s1 = (g + 4 < dg) ? csr[off + g + 4] : N;
    for (int j = 0; j < dg; j += 8) {
        int j2 = j + 8;
        int sn0 = (j2 + g < dg) ? csr[off + j2 + g] : N;
        int sn1 = (j2 + 4 + g < dg) ? csr[off + j2 + 4 + g] : N;
        u16x8 v0 = XB[(size_t)s0 * 16 + c];
        u16x8 v1 = XB[(size_t)s1 * 16 + c];
#pragma unroll
        for (int k = 0; k < 8; k++) acc[k] += bf2f(v0[k]) + bf2f(v1[k]);
        s0 = sn0; s1 = sn1;
    }
#pragma unroll
    for (int k = 0; k < 8; k++) {
        acc[k] += __shfl_xor(acc[k], 16);
        acc[k] += __shfl_xor(acc[k], 32);
    }
    float dc = dis[node];
    u16x8 xv = XB[(size_t)node * 16 + c];
    if (lane < 16) {
        u16x8 o;
#pragma unroll
        for (int k = 0; k < 8; k++) o[k] = f2bf(dc * (acc[k] + bf2f(xv[k])));
        ((u16x8*)xa)[(size_t)node * 16 + c] = o;
    }
}

// ---------------- fused MLP (MFMA): h2s = dis .* relu(xa@W1+b1) @ W2 ----------------
// 256 thr = 4 waves; block tile 64 rows. a1 lives only in LDS.
__global__ __launch_bounds__(256) void mlp_kernel(const unsigned short* __restrict__ xa,
                                                  const unsigned short* __restrict__ w1p,
                                                  const unsigned short* __restrict__ w2p,
                                                  const float* __restrict__ b1,
                                                  const float* __restrict__ dis,
                                                  unsigned short* __restrict__ h2s, int N) {
    __shared__ unsigned short a1s[64][136];  // +8 pad: 2-way (free) LDS banking
    int wv = threadIdx.x >> 6;
    int l = threadIdx.x & 63;
    int row16 = l & 15, kg = l >> 4;
    int n0 = blockIdx.x * 64;
    int rbase = n0 + wv * 16;

    // phase 1: acc[ct] = xa_tile @ W1  (16 rows x 128 cols per wave)
    f32x4 acc[8];
#pragma unroll
    for (int ct = 0; ct < 8; ct++) acc[ct] = (f32x4)0.f;
    int r = rbase + row16;
    int rc = (r < N) ? r : (N - 1);  // clamp; out-of-range rows discarded later
#pragma unroll
    for (int kc = 0; kc < 4; kc++) {
        s16x8 af = *(const s16x8*)(xa + (size_t)rc * 128 + kc * 32 + kg * 8);
#pragma unroll
        for (int ct = 0; ct < 8; ct++) {
            s16x8 bf = *(const s16x8*)(w1p + (size_t)((ct * 4 + kc) * 64 + l) * 8);
            acc[ct] = __builtin_amdgcn_mfma_f32_16x16x32_bf16(af, bf, acc[ct], 0, 0, 0);
        }
    }
    // epilogue 1: bias + relu -> LDS bf16   (D: col=lane&15, row=(lane>>4)*4+v)
#pragma unroll
    for (int ct = 0; ct < 8; ct++) {
        float bb = b1[ct * 16 + row16];
#pragma unroll
        for (int v = 0; v < 4; v++)
            a1s[wv * 16 + kg * 4 + v][ct * 16 + row16] = f2bf(fmaxf(acc[ct][v] + bb, 0.f));
    }
    __syncthreads();

    // phase 2: acc2[ct] = a1_tile @ W2 (48 padded cols)
    f32x4 acc2[3];
#pragma unroll
    for (int ct = 0; ct < 3; ct++) acc2[ct] = (f32x4)0.f;
#pragma unroll
    for (int kc = 0; kc < 4; kc++) {
        s16x8 af = *(const s16x8*)&a1s[wv * 16 + row16][kc * 32 + kg * 8];
#pragma unroll
        for (int ct = 0; ct < 3; ct++) {
            s16x8 bf = *(const s16x8*)(w2p + (size_t)((ct * 4 + kc) * 64 + l) * 8);
            acc2[ct] = __builtin_amdgcn_mfma_f32_16x16x32_bf16(af, bf, acc2[ct], 0, 0, 0);
        }
    }
    // epilogue 2: scale by dis, store bf16 (cols 0..47 of 64-padded row)
#pragma unroll
    for (int v = 0; v < 4; v++) {
        int rr = rbase + kg * 4 + v;
        if (rr < N) {
            float d = dis[rr];
#pragma unroll
            for (int ct = 0; ct < 3; ct++)
                h2s[(size_t)rr * 64 + ct * 16 + row16] = f2bf(d * acc2[ct][v]);
        }
    }
}

// ---------------- gather2: log_softmax(dc*(sum_s h2s[s] + h2s[node]) + b2), 8 edges in flight ----------------
__global__ void gather2_kernel(const unsigned short* __restrict__ h2s, const int* __restrict__ offs,
                               const int* __restrict__ cnt, const int* __restrict__ csr,
                               const float* __restrict__ dis, const float* __restrict__ b2,
                               float* __restrict__ out, int N) {
    int node = blockIdx.x * 4 + (threadIdx.x >> 6);
    int lane = threadIdx.x & 63;
    if (node >= N) return;
    int off = offs[node], dg = cnt[node];
    int g = lane >> 5, c = lane & 31;
    const unsigned* H32 = (const unsigned*)h2s;
    float a0 = 0.f, a1 = 0.f;
    int s0 = (g < dg) ? csr[off + g] : N;
    int s1 = (g + 2 < dg) ? csr[off + g + 2] : N;
    int s2 = (g + 4 < dg) ? csr[off + g + 4] : N;
    int s3 = (g + 6 < dg) ? csr[off + g + 6] : N;
    for (int j = 0; j < dg; j += 8) {
        int jb = j + 8;
        int t0 = (jb + g < dg) ? csr[off + jb + g] : N;
        int t1 = (jb + 2 + g < dg) ? csr[off + jb + 2 + g] : N;
        int t2 = (jb + 4 + g < dg) ? csr[off + jb + 4 + g] : N;
        int t3 = (jb + 6 + g < dg) ? csr[off + jb + 6 + g] : N;
        unsigned u0 = H32[(size_t)s0 * 32 + c];
        unsigned u1 = H32[(size_t)s1 * 32 + c];
        unsigned u2 = H32[(size_t)s2 * 32 + c];
        unsigned u3 = H32[(size_t)s3 * 32 + c];
        a0 += bf2f(u0 & 0xffffu) + bf2f(u1 & 0xffffu) + bf2f(u2 & 0xffffu) + bf2f(u3 & 0xffffu);
        a1 += bf2f(u0 >> 16) + bf2f(u1 >> 16) + bf2f(u2 >> 16) + bf2f(u3 >> 16);
        s0 = t0; s1 = t1; s2 = t2; s3 = t3;
    }
    a0 += __shfl_xor(a0, 32);
    a1 += __shfl_xor(a1, 32);
    float dc = dis[node];
    bool act = c < 20;
    unsigned u = H32[(size_t)node * 32 + c];
    float v0 = act ? (dc * (a0 + bf2f(u & 0xffffu)) + b2[2 * c]) : -INFINITY;
    float v1 = act ? (dc * (a1 + bf2f(u >> 16)) + b2[2 * c + 1]) : -INFINITY;
    float m = fmaxf(v0, v1);
#pragma unroll
    for (int o = 32; o > 0; o >>= 1) m = fmaxf(m, __shfl_xor(m, o));
    // both 32-lane halves hold identical v after the fold -> denominator counted twice
    float ex = act ? (__expf(v0 - m) + __expf(v1 - m)) : 0.f;
#pragma unroll
    for (int o = 32; o > 0; o >>= 1) ex += __shfl_xor(ex, o);
    float ls = __logf(0.5f * ex);
    if (lane < 20) {
        float2 o2 = make_float2(v0 - m - ls, v1 - m - ls);
        ((float2*)(out + (size_t)node * 40))[c] = o2;
    }
}

extern "C" void kernel_launch(void* const* d_in, const int* in_sizes, int n_in,
                              void* d_out, int out_size, void* d_ws, size_t ws_size,
                              hipStream_t stream) {
    const float* x  = (const float*)d_in[0];
    const int*   ei = (const int*)d_in[1];
    const float* W1 = (const float*)d_in[2];
    const float* b1 = (const float*)d_in[3];
    const float* W2 = (const float*)d_in[4];
    const float* b2 = (const float*)d_in[5];
    float* out = (float*)d_out;

    const int N = in_sizes[0] / 128;
    const int E = in_sizes[1] / 2;
    const int* row = ei;
    const int* col = ei + E;

    const int Npad = (N + 511) & ~511;
    const int Epad = (E + 511) & ~511;
    const int nb = (N + SCAN_B - 1) / SCAN_B;
    const int NB = (N + 255) >> 8;

    int* cnt      = (int*)d_ws;           // Npad
    int* offs     = cnt + Npad;           // Npad
    int* cursor   = offs + Npad;          // Npad
    int* blockSum = cursor + Npad;        // 512
    int* bcur     = blockSum + 512;       // 512
    int* csr      = bcur + 512;           // Epad
    unsigned* tmp = (unsigned*)(csr + Epad);              // Epad
    float* dis    = (float*)(tmp + Epad); // Npad
    unsigned short* w1p = (unsigned short*)(dis + Npad);  // 16384
    unsigned short* w2p = w1p + 16384;                    // 6144 (+pad to 8192)
    unsigned short* xbs = w2p + 8192;                     // (N+1)*128 bf16
    unsigned short* xa  = xbs + (size_t)(N + 1) * 128;    // N*128 bf16
    unsigned short* h2s = xa + (size_t)N * 128;           // (N+1)*64 bf16

    // 1) degrees
    hipMemsetAsync(cnt, 0, (size_t)N * sizeof(int), stream);
    count_deg_kernel<<<(E + 255) / 256, 256, 0, stream>>>(col, cnt, E);
    dis_kernel<<<(N + 255) / 256, 256, 0, stream>>>(cnt, dis, N);

    // 2) CSR by destination: scan + binned 2-pass counting sort
    scan1_kernel<<<nb, SCAN_B, 0, stream>>>(cnt, offs, blockSum, N);
    scan2_kernel<<<1, SCAN_B, 0, stream>>>(blockSum, nb);
    scan3_kernel<<<(N + 255) / 256, 256, 0, stream>>>(offs, blockSum, cursor, bcur, N);
    bin_kernel<<<(E + BIN_TILE - 1) / BIN_TILE, 256, 0, stream>>>(row, col, bcur, tmp, E, NB);
    scatter_kernel<<<NB, 256, 0, stream>>>(tmp, offs, cursor, csr, E, N);

    // 3) weight packs + h2s sentinel + pre-scaled bf16 features
    w1pack_kernel<<<8, 256, 0, stream>>>(W1, w1p);
    w2pack_kernel<<<3, 256, 0, stream>>>(W2, w2p);
    zrow_kernel<<<1, 64, 0, stream>>>((unsigned*)(h2s + (size_t)N * 64));
    {
        long total8 = (long)(N + 1) * 16;
        scale_cvt_kernel<<<(int)((total8 + 255) / 256), 256, 0, stream>>>(x, dis, xbs, N);
    }

    // 4) xa = Dc * (sum + self) on pre-scaled rows
    gather1_kernel<<<(N + 3) / 4, 256, 0, stream>>>(xbs, offs, cnt, csr, dis, xa, N);

    // 5) h2s = dis .* (relu(xa@W1+b1) @ W2)   (fused, a1 only in LDS)
    mlp_kernel<<<(N + 63) / 64, 256, 0, stream>>>(xa, w1p, w2p, b1, dis, h2s, N);

    // 6) out = log_softmax(dc*(sum + self) + b2)
    gather2_kernel<<<(N + 3) / 4, 256, 0, stream>>>(h2s, offs, cnt, csr, dis, b2, out, N);
}

// Round 7
// 210.875 us; speedup vs baseline: 5.6886x; 1.3584x over previous
//
#include <hip/hip_runtime.h>
#include <hip/hip_bf16.h>
#include <math.h>

typedef unsigned short u16x8 __attribute__((ext_vector_type(8)));
typedef short s16x8 __attribute__((ext_vector_type(8)));
typedef float f32x4 __attribute__((ext_vector_type(4)));

__device__ __forceinline__ float bf2f(unsigned int u) {
    union { unsigned int i; float f; } x;
    x.i = u << 16;
    return x.f;
}
__device__ __forceinline__ unsigned short f2bf(float f) {
    __hip_bfloat16 h = __float2bfloat16(f);
    return *reinterpret_cast<unsigned short*>(&h);
}

// ---------------- bucket histogram: btot[b] += #edges with col>>8 == b ----------------
#define BIN_TILE 4096
__global__ void hist_kernel(const int* __restrict__ col, int* __restrict__ btot, int E, int NB) {
    __shared__ int hist[512];
    int tid = threadIdx.x;
    int base = blockIdx.x * BIN_TILE;
    for (int i = tid; i < NB; i += 256) hist[i] = 0;
    __syncthreads();
#pragma unroll
    for (int i = 0; i < BIN_TILE / 256; i++) {
        int e = base + tid + i * 256;
        if (e < E) atomicAdd(&hist[col[e] >> 8], 1);
    }
    __syncthreads();
    for (int i = tid; i < NB; i += 256)
        if (hist[i]) atomicAdd(&btot[i], hist[i]);
}

// ---------------- bucket scan (1 block): boffs[0..NB], bcur copy ----------------
__global__ void bscan_kernel(const int* __restrict__ btot, int* __restrict__ boffs,
                             int* __restrict__ bcur, int NB, int E) {
    __shared__ int s[512];
    int tid = threadIdx.x;
    int v = (tid < NB) ? btot[tid] : 0;
    s[tid] = v;
    __syncthreads();
    for (int off = 1; off < 512; off <<= 1) {
        int t = (tid >= off) ? s[tid - off] : 0;
        __syncthreads();
        s[tid] += t;
        __syncthreads();
    }
    if (tid < NB) {
        int ex = s[tid] - v;
        boffs[tid] = ex;
        bcur[tid] = ex;
    }
    if (tid == NB - 1) boffs[NB] = s[tid];  // == E
}

// ---------------- binned CSR build, pass 1: edges -> bucket-contiguous tmp ----------------
// tmp entry = row | (col&255)<<20
__global__ void bin_kernel(const int* __restrict__ row, const int* __restrict__ col,
                           int* __restrict__ bcur, unsigned* __restrict__ tmp, int E, int NB) {
    __shared__ unsigned hist[512];
    int tid = threadIdx.x;
    int base = blockIdx.x * BIN_TILE;
    for (int i = tid; i < NB; i += 256) hist[i] = 0;
    __syncthreads();
#pragma unroll
    for (int i = 0; i < BIN_TILE / 256; i++) {
        int e = base + tid + i * 256;
        if (e < E) atomicAdd(&hist[col[e] >> 8], 1u);
    }
    __syncthreads();
    for (int i = tid; i < NB; i += 256) {
        unsigned h = hist[i];
        hist[i] = h ? (unsigned)atomicAdd(&bcur[i], (int)h) : 0u;
    }
    __syncthreads();
#pragma unroll
    for (int i = 0; i < BIN_TILE / 256; i++) {
        int e = base + tid + i * 256;
        if (e < E) {
            int c = col[e], r = row[e];
            unsigned p = atomicAdd(&hist[c >> 8], 1u);
            tmp[p] = (unsigned)r | ((unsigned)(c & 255) << 20);
        }
    }
}

// ---------------- pass 2: per bucket -> cnt/offs/dis + fine scatter, all LDS-local ----------------
__global__ void bucket_kernel(const unsigned* __restrict__ tmp, const int* __restrict__ boffs,
                              int* __restrict__ cnt, int* __restrict__ offs,
                              float* __restrict__ dis, int* __restrict__ csr, int N) {
    __shared__ int cntS[256], curS[256], sA[256], sB[256];
    int b = blockIdx.x;
    int tid = threadIdx.x;
    int start = boffs[b];
    int end = boffs[b + 1];
    cntS[tid] = 0;
    __syncthreads();
    for (int i = start + tid; i < end; i += 256)
        atomicAdd(&cntS[(tmp[i] >> 20) & 255], 1);
    __syncthreads();
    int myCnt = cntS[tid];
    // exclusive scan over 256 (ping-pong Hillis-Steele)
    sA[tid] = myCnt;
    __syncthreads();
    int* src = sA;
    int* dst = sB;
    for (int off = 1; off < 256; off <<= 1) {
        dst[tid] = src[tid] + ((tid >= off) ? src[tid - off] : 0);
        __syncthreads();
        int* t = src; src = dst; dst = t;
    }
    int excl = src[tid] - myCnt;
    int node = (b << 8) + tid;
    if (node < N) {
        cnt[node] = myCnt;
        offs[node] = start + excl;
        dis[node] = rsqrtf((float)myCnt + 1.0f);
    }
    curS[tid] = excl;
    __syncthreads();
    for (int i = start + tid; i < end; i += 256) {
        unsigned u = tmp[i];
        int cl = (u >> 20) & 255;
        int p = atomicAdd(&curS[cl], 1);
        csr[start + p] = (int)(u & 0xFFFFFu);
    }
}

// ---------------- xbs[i] = bf16(dis[i]*x[i]); sentinel row N = 0 ----------------
__global__ void scale_cvt_kernel(const float* __restrict__ x, const float* __restrict__ dis,
                                 unsigned short* __restrict__ xbs, int N) {
    long idx = (long)blockIdx.x * blockDim.x + threadIdx.x;  // one u16x8 chunk
    long total8 = (long)(N + 1) * 16;
    if (idx >= total8) return;
    int i = (int)(idx >> 4);
    u16x8 o;
    if (i >= N) {
#pragma unroll
        for (int k = 0; k < 8; k++) o[k] = 0;
    } else {
        float d = dis[i];
        float4 a = ((const float4*)x)[2 * idx];
        float4 b = ((const float4*)x)[2 * idx + 1];
        o[0] = f2bf(d * a.x); o[1] = f2bf(d * a.y); o[2] = f2bf(d * a.z); o[3] = f2bf(d * a.w);
        o[4] = f2bf(d * b.x); o[5] = f2bf(d * b.y); o[6] = f2bf(d * b.z); o[7] = f2bf(d * b.w);
    }
    ((u16x8*)xbs)[idx] = o;
}

// ---------------- zero h2s sentinel row N ----------------
__global__ void zrow_kernel(unsigned* __restrict__ p32) {
    if (threadIdx.x < 32) p32[threadIdx.x] = 0;
}

// ---------------- W packs into MFMA B-fragment order ----------------
__global__ void w1pack_kernel(const float* __restrict__ W, unsigned short* __restrict__ wp) {
    int t = blockIdx.x * blockDim.x + threadIdx.x;
    if (t >= 2048) return;
    int lane = t & 63, fc = t >> 6;
    int ct = fc >> 2, kc = fc & 3;
    int n = ct * 16 + (lane & 15);
    int k0 = kc * 32 + (lane >> 4) * 8;
    u16x8 o;
#pragma unroll
    for (int j = 0; j < 8; j++) o[j] = f2bf(W[(size_t)(k0 + j) * 128 + n]);
    ((u16x8*)wp)[t] = o;
}

__global__ void w2pack_kernel(const float* __restrict__ W, unsigned short* __restrict__ wp) {
    int t = blockIdx.x * blockDim.x + threadIdx.x;
    if (t >= 768) return;
    int lane = t & 63, fc = t >> 6;
    int ct = fc >> 2, kc = fc & 3;
    int n = ct * 16 + (lane & 15);
    int k0 = kc * 32 + (lane >> 4) * 8;
    u16x8 o;
#pragma unroll
    for (int j = 0; j < 8; j++) o[j] = (n < 40) ? f2bf(W[(size_t)(k0 + j) * 40 + n]) : (unsigned short)0;
    ((u16x8*)wp)[t] = o;
}

// ---------------- gather1: xa[c] = dc * ( sum_s xbs[s] + xbs[c] ), 8 edges in flight ----------------
__global__ void gather1_kernel(const unsigned short* __restrict__ xbs, const int* __restrict__ offs,
                               const int* __restrict__ cnt, const int* __restrict__ csr,
                               const float* __restrict__ dis, unsigned short* __restrict__ xa, int N) {
    int node = blockIdx.x * 4 + (threadIdx.x >> 6);
    int lane = threadIdx.x & 63;
    if (node >= N) return;
    int off = offs[node], dg = cnt[node];
    int g = lane >> 4, c = lane & 15;
    const u16x8* XB = (const u16x8*)xbs;
    float acc[8] = {};
    int s0 = (g < dg) ? csr[off + g] : N;
    int s1 = (g + 4 < dg) ? csr[off + g + 4] : N;
    for (int j = 0; j < dg; j += 8) {
        int j2 = j + 8;
        int sn0 = (j2 + g < dg) ? csr[off + j2 + g] : N;
        int sn1 = (j2 + 4 + g < dg) ? csr[off + j2 + 4 + g] : N;
        u16x8 v0 = XB[(size_t)s0 * 16 + c];
        u16x8 v1 = XB[(size_t)s1 * 16 + c];
#pragma unroll
        for (int k = 0; k < 8; k++) acc[k] += bf2f(v0[k]) + bf2f(v1[k]);
        s0 = sn0; s1 = sn1;
    }
#pragma unroll
    for (int k = 0; k < 8; k++) {
        acc[k] += __shfl_xor(acc[k], 16);
        acc[k] += __shfl_xor(acc[k], 32);
    }
    float dc = dis[node];
    u16x8 xv = XB[(size_t)node * 16 + c];
    if (lane < 16) {
        u16x8 o;
#pragma unroll
        for (int k = 0; k < 8; k++) o[k] = f2bf(dc * (acc[k] + bf2f(xv[k])));
        ((u16x8*)xa)[(size_t)node * 16 + c] = o;
    }
}

// ---------------- fused MLP (MFMA): h2s = dis .* relu(xa@W1+b1) @ W2 ----------------
__global__ __launch_bounds__(256) void mlp_kernel(const unsigned short* __restrict__ xa,
                                                  const unsigned short* __restrict__ w1p,
                                                  const unsigned short* __restrict__ w2p,
                                                  const float* __restrict__ b1,
                                                  const float* __restrict__ dis,
                                                  unsigned short* __restrict__ h2s, int N) {
    __shared__ unsigned short a1s[64][136];
    int wv = threadIdx.x >> 6;
    int l = threadIdx.x & 63;
    int row16 = l & 15, kg = l >> 4;
    int n0 = blockIdx.x * 64;
    int rbase = n0 + wv * 16;

    f32x4 acc[8];
#pragma unroll
    for (int ct = 0; ct < 8; ct++) acc[ct] = (f32x4)0.f;
    int r = rbase + row16;
    int rc = (r < N) ? r : (N - 1);
#pragma unroll
    for (int kc = 0; kc < 4; kc++) {
        s16x8 af = *(const s16x8*)(xa + (size_t)rc * 128 + kc * 32 + kg * 8);
#pragma unroll
        for (int ct = 0; ct < 8; ct++) {
            s16x8 bf = *(const s16x8*)(w1p + (size_t)((ct * 4 + kc) * 64 + l) * 8);
            acc[ct] = __builtin_amdgcn_mfma_f32_16x16x32_bf16(af, bf, acc[ct], 0, 0, 0);
        }
    }
#pragma unroll
    for (int ct = 0; ct < 8; ct++) {
        float bb = b1[ct * 16 + row16];
#pragma unroll
        for (int v = 0; v < 4; v++)
            a1s[wv * 16 + kg * 4 + v][ct * 16 + row16] = f2bf(fmaxf(acc[ct][v] + bb, 0.f));
    }
    __syncthreads();

    f32x4 acc2[3];
#pragma unroll
    for (int ct = 0; ct < 3; ct++) acc2[ct] = (f32x4)0.f;
#pragma unroll
    for (int kc = 0; kc < 4; kc++) {
        s16x8 af = *(const s16x8*)&a1s[wv * 16 + row16][kc * 32 + kg * 8];
#pragma unroll
        for (int ct = 0; ct < 3; ct++) {
            s16x8 bf = *(const s16x8*)(w2p + (size_t)((ct * 4 + kc) * 64 + l) * 8);
            acc2[ct] = __builtin_amdgcn_mfma_f32_16x16x32_bf16(af, bf, acc2[ct], 0, 0, 0);
        }
    }
#pragma unroll
    for (int v = 0; v < 4; v++) {
        int rr = rbase + kg * 4 + v;
        if (rr < N) {
            float d = dis[rr];
#pragma unroll
            for (int ct = 0; ct < 3; ct++)
                h2s[(size_t)rr * 64 + ct * 16 + row16] = f2bf(d * acc2[ct][v]);
        }
    }
}

// ---------------- gather2: log_softmax(dc*(sum_s h2s[s] + h2s[node]) + b2), 8 edges in flight ----------------
__global__ void gather2_kernel(const unsigned short* __restrict__ h2s, const int* __restrict__ offs,
                               const int* __restrict__ cnt, const int* __restrict__ csr,
                               const float* __restrict__ dis, const float* __restrict__ b2,
                               float* __restrict__ out, int N) {
    int node = blockIdx.x * 4 + (threadIdx.x >> 6);
    int lane = threadIdx.x & 63;
    if (node >= N) return;
    int off = offs[node], dg = cnt[node];
    int g = lane >> 5, c = lane & 31;
    const unsigned* H32 = (const unsigned*)h2s;
    float a0 = 0.f, a1 = 0.f;
    int s0 = (g < dg) ? csr[off + g] : N;
    int s1 = (g + 2 < dg) ? csr[off + g + 2] : N;
    int s2 = (g + 4 < dg) ? csr[off + g + 4] : N;
    int s3 = (g + 6 < dg) ? csr[off + g + 6] : N;
    for (int j = 0; j < dg; j += 8) {
        int jb = j + 8;
        int t0 = (jb + g < dg) ? csr[off + jb + g] : N;
        int t1 = (jb + 2 + g < dg) ? csr[off + jb + 2 + g] : N;
        int t2 = (jb + 4 + g < dg) ? csr[off + jb + 4 + g] : N;
        int t3 = (jb + 6 + g < dg) ? csr[off + jb + 6 + g] : N;
        unsigned u0 = H32[(size_t)s0 * 32 + c];
        unsigned u1 = H32[(size_t)s1 * 32 + c];
        unsigned u2 = H32[(size_t)s2 * 32 + c];
        unsigned u3 = H32[(size_t)s3 * 32 + c];
        a0 += bf2f(u0 & 0xffffu) + bf2f(u1 & 0xffffu) + bf2f(u2 & 0xffffu) + bf2f(u3 & 0xffffu);
        a1 += bf2f(u0 >> 16) + bf2f(u1 >> 16) + bf2f(u2 >> 16) + bf2f(u3 >> 16);
        s0 = t0; s1 = t1; s2 = t2; s3 = t3;
    }
    a0 += __shfl_xor(a0, 32);
    a1 += __shfl_xor(a1, 32);
    float dc = dis[node];
    bool act = c < 20;
    unsigned u = H32[(size_t)node * 32 + c];
    float v0 = act ? (dc * (a0 + bf2f(u & 0xffffu)) + b2[2 * c]) : -INFINITY;
    float v1 = act ? (dc * (a1 + bf2f(u >> 16)) + b2[2 * c + 1]) : -INFINITY;
    float m = fmaxf(v0, v1);
#pragma unroll
    for (int o = 32; o > 0; o >>= 1) m = fmaxf(m, __shfl_xor(m, o));
    float ex = act ? (__expf(v0 - m) + __expf(v1 - m)) : 0.f;
#pragma unroll
    for (int o = 32; o > 0; o >>= 1) ex += __shfl_xor(ex, o);
    float ls = __logf(0.5f * ex);  // both 32-lane halves identical -> denom counted twice
    if (lane < 20) {
        float2 o2 = make_float2(v0 - m - ls, v1 - m - ls);
        ((float2*)(out + (size_t)node * 40))[c] = o2;
    }
}

extern "C" void kernel_launch(void* const* d_in, const int* in_sizes, int n_in,
                              void* d_out, int out_size, void* d_ws, size_t ws_size,
                              hipStream_t stream) {
    const float* x  = (const float*)d_in[0];
    const int*   ei = (const int*)d_in[1];
    const float* W1 = (const float*)d_in[2];
    const float* b1 = (const float*)d_in[3];
    const float* W2 = (const float*)d_in[4];
    const float* b2 = (const float*)d_in[5];
    float* out = (float*)d_out;

    const int N = in_sizes[0] / 128;
    const int E = in_sizes[1] / 2;
    const int* row = ei;
    const int* col = ei + E;

    const int Npad = (N + 511) & ~511;
    const int Epad = (E + 511) & ~511;
    const int NB = (N + 255) >> 8;  // coarse buckets (col>>8); <=512

    int* cnt      = (int*)d_ws;           // Npad
    int* offs     = cnt + Npad;           // Npad
    int* btot     = offs + Npad;          // 512
    int* boffs    = btot + 512;           // 513 (pad 1024)
    int* bcur     = boffs + 1024;         // 512
    int* csr      = bcur + 512;           // Epad
    unsigned* tmp = (unsigned*)(csr + Epad);              // Epad
    float* dis    = (float*)(tmp + Epad); // Npad
    unsigned short* w1p = (unsigned short*)(dis + Npad);  // 16384
    unsigned short* w2p = w1p + 16384;                    // 6144 (pad 8192)
    unsigned short* xbs = w2p + 8192;                     // (N+1)*128 bf16
    unsigned short* xa  = xbs + (size_t)(N + 1) * 128;    // N*128 bf16
    unsigned short* h2s = xa + (size_t)N * 128;           // (N+1)*64 bf16

    // 1) CSR build: bucket histogram -> bucket scan -> bin -> per-bucket count/scan/scatter
    hipMemsetAsync(btot, 0, 512 * sizeof(int), stream);
    hist_kernel<<<(E + BIN_TILE - 1) / BIN_TILE, 256, 0, stream>>>(col, btot, E, NB);
    bscan_kernel<<<1, 512, 0, stream>>>(btot, boffs, bcur, NB, E);
    bin_kernel<<<(E + BIN_TILE - 1) / BIN_TILE, 256, 0, stream>>>(row, col, bcur, tmp, E, NB);
    bucket_kernel<<<NB, 256, 0, stream>>>(tmp, boffs, cnt, offs, dis, csr, N);

    // 2) weight packs + h2s sentinel + pre-scaled bf16 features
    w1pack_kernel<<<8, 256, 0, stream>>>(W1, w1p);
    w2pack_kernel<<<3, 256, 0, stream>>>(W2, w2p);
    zrow_kernel<<<1, 64, 0, stream>>>((unsigned*)(h2s + (size_t)N * 64));
    {
        long total8 = (long)(N + 1) * 16;
        scale_cvt_kernel<<<(int)((total8 + 255) / 256), 256, 0, stream>>>(x, dis, xbs, N);
    }

    // 3) xa = Dc * (sum + self) on pre-scaled rows
    gather1_kernel<<<(N + 3) / 4, 256, 0, stream>>>(xbs, offs, cnt, csr, dis, xa, N);

    // 4) h2s = dis .* (relu(xa@W1+b1) @ W2)   (fused, a1 only in LDS)
    mlp_kernel<<<(N + 63) / 64, 256, 0, stream>>>(xa, w1p, w2p, b1, dis, h2s, N);

    // 5) out = log_softmax(dc*(sum + self) + b2)
    gather2_kernel<<<(N + 3) / 4, 256, 0, stream>>>(h2s, offs, cnt, csr, dis, b2, out, N);
}

// Round 8
// 202.443 us; speedup vs baseline: 5.9255x; 1.0417x over previous
//
#include <hip/hip_runtime.h>
#include <hip/hip_bf16.h>
#include <math.h>

typedef unsigned short u16x8 __attribute__((ext_vector_type(8)));
typedef short s16x8 __attribute__((ext_vector_type(8)));
typedef float f32x4 __attribute__((ext_vector_type(4)));

__device__ __forceinline__ float bf2f(unsigned int u) {
    union { unsigned int i; float f; } x;
    x.i = u << 16;
    return x.f;
}
__device__ __forceinline__ unsigned short f2bf(float f) {
    __hip_bfloat16 h = __float2bfloat16(f);
    return *reinterpret_cast<unsigned short*>(&h);
}

// ---------------- bucket histogram: btot[b] += #edges with col>>8 == b ----------------
#define BIN_TILE 4096
__global__ void hist_kernel(const int* __restrict__ col, int* __restrict__ btot, int E, int NB) {
    __shared__ int hist[512];
    int tid = threadIdx.x;
    int base = blockIdx.x * BIN_TILE;
    for (int i = tid; i < NB; i += 256) hist[i] = 0;
    __syncthreads();
#pragma unroll
    for (int i = 0; i < BIN_TILE / 256; i++) {
        int e = base + tid + i * 256;
        if (e < E) atomicAdd(&hist[col[e] >> 8], 1);
    }
    __syncthreads();
    for (int i = tid; i < NB; i += 256)
        if (hist[i]) atomicAdd(&btot[i], hist[i]);
}

// ---------------- bucket scan (1 block): boffs[0..NB], bcur copy ----------------
__global__ void bscan_kernel(const int* __restrict__ btot, int* __restrict__ boffs,
                             int* __restrict__ bcur, int NB, int E) {
    __shared__ int s[512];
    int tid = threadIdx.x;
    int v = (tid < NB) ? btot[tid] : 0;
    s[tid] = v;
    __syncthreads();
    for (int off = 1; off < 512; off <<= 1) {
        int t = (tid >= off) ? s[tid - off] : 0;
        __syncthreads();
        s[tid] += t;
        __syncthreads();
    }
    if (tid < NB) {
        int ex = s[tid] - v;
        boffs[tid] = ex;
        bcur[tid] = ex;
    }
    if (tid == NB - 1) boffs[NB] = s[tid];  // == E
}

// ---------------- binned CSR build, pass 1: edges -> bucket-contiguous tmp ----------------
// tmp entry = row | (col&255)<<20
__global__ void bin_kernel(const int* __restrict__ row, const int* __restrict__ col,
                           int* __restrict__ bcur, unsigned* __restrict__ tmp, int E, int NB) {
    __shared__ unsigned hist[512];
    int tid = threadIdx.x;
    int base = blockIdx.x * BIN_TILE;
    for (int i = tid; i < NB; i += 256) hist[i] = 0;
    __syncthreads();
#pragma unroll
    for (int i = 0; i < BIN_TILE / 256; i++) {
        int e = base + tid + i * 256;
        if (e < E) atomicAdd(&hist[col[e] >> 8], 1u);
    }
    __syncthreads();
    for (int i = tid; i < NB; i += 256) {
        unsigned h = hist[i];
        hist[i] = h ? (unsigned)atomicAdd(&bcur[i], (int)h) : 0u;
    }
    __syncthreads();
#pragma unroll
    for (int i = 0; i < BIN_TILE / 256; i++) {
        int e = base + tid + i * 256;
        if (e < E) {
            int c = col[e], r = row[e];
            unsigned p = atomicAdd(&hist[c >> 8], 1u);
            tmp[p] = (unsigned)r | ((unsigned)(c & 255) << 20);
        }
    }
}

// ---------------- pass 2: per bucket -> cnt/offs/dis + fine scatter, all LDS-local ----------------
__global__ void bucket_kernel(const unsigned* __restrict__ tmp, const int* __restrict__ boffs,
                              int* __restrict__ cnt, int* __restrict__ offs,
                              float* __restrict__ dis, int* __restrict__ csr, int N) {
    __shared__ int cntS[256], curS[256], sA[256], sB[256];
    int b = blockIdx.x;
    int tid = threadIdx.x;
    int start = boffs[b];
    int end = boffs[b + 1];
    cntS[tid] = 0;
    __syncthreads();
    for (int i = start + tid; i < end; i += 256)
        atomicAdd(&cntS[(tmp[i] >> 20) & 255], 1);
    __syncthreads();
    int myCnt = cntS[tid];
    sA[tid] = myCnt;
    __syncthreads();
    int* src = sA;
    int* dst = sB;
    for (int off = 1; off < 256; off <<= 1) {
        dst[tid] = src[tid] + ((tid >= off) ? src[tid - off] : 0);
        __syncthreads();
        int* t = src; src = dst; dst = t;
    }
    int excl = src[tid] - myCnt;
    int node = (b << 8) + tid;
    if (node < N) {
        cnt[node] = myCnt;
        offs[node] = start + excl;
        dis[node] = rsqrtf((float)myCnt + 1.0f);
    }
    curS[tid] = excl;
    __syncthreads();
    for (int i = start + tid; i < end; i += 256) {
        unsigned u = tmp[i];
        int cl = (u >> 20) & 255;
        int p = atomicAdd(&curS[cl], 1);
        csr[start + p] = (int)(u & 0xFFFFFu);
    }
}

// ---------------- xbs[i] = bf16(dis[i]*x[i]); sentinel row N = 0 ----------------
__global__ void scale_cvt_kernel(const float* __restrict__ x, const float* __restrict__ dis,
                                 unsigned short* __restrict__ xbs, int N) {
    long idx = (long)blockIdx.x * blockDim.x + threadIdx.x;  // one u16x8 chunk
    long total8 = (long)(N + 1) * 16;
    if (idx >= total8) return;
    int i = (int)(idx >> 4);
    u16x8 o;
    if (i >= N) {
#pragma unroll
        for (int k = 0; k < 8; k++) o[k] = 0;
    } else {
        float d = dis[i];
        float4 a = ((const float4*)x)[2 * idx];
        float4 b = ((const float4*)x)[2 * idx + 1];
        o[0] = f2bf(d * a.x); o[1] = f2bf(d * a.y); o[2] = f2bf(d * a.z); o[3] = f2bf(d * a.w);
        o[4] = f2bf(d * b.x); o[5] = f2bf(d * b.y); o[6] = f2bf(d * b.z); o[7] = f2bf(d * b.w);
    }
    ((u16x8*)xbs)[idx] = o;
}

// ---------------- zero h2s sentinel row N ----------------
__global__ void zrow_kernel(unsigned* __restrict__ p32) {
    if (threadIdx.x < 32) p32[threadIdx.x] = 0;
}

// ---------------- W packs into MFMA B-fragment order ----------------
__global__ void w1pack_kernel(const float* __restrict__ W, unsigned short* __restrict__ wp) {
    int t = blockIdx.x * blockDim.x + threadIdx.x;
    if (t >= 2048) return;
    int lane = t & 63, fc = t >> 6;
    int ct = fc >> 2, kc = fc & 3;
    int n = ct * 16 + (lane & 15);
    int k0 = kc * 32 + (lane >> 4) * 8;
    u16x8 o;
#pragma unroll
    for (int j = 0; j < 8; j++) o[j] = f2bf(W[(size_t)(k0 + j) * 128 + n]);
    ((u16x8*)wp)[t] = o;
}

__global__ void w2pack_kernel(const float* __restrict__ W, unsigned short* __restrict__ wp) {
    int t = blockIdx.x * blockDim.x + threadIdx.x;
    if (t >= 768) return;
    int lane = t & 63, fc = t >> 6;
    int ct = fc >> 2, kc = fc & 3;
    int n = ct * 16 + (lane & 15);
    int k0 = kc * 32 + (lane >> 4) * 8;
    u16x8 o;
#pragma unroll
    for (int j = 0; j < 8; j++) o[j] = (n < 40) ? f2bf(W[(size_t)(k0 + j) * 40 + n]) : (unsigned short)0;
    ((u16x8*)wp)[t] = o;
}

// ---------------- gather1: xa[c] = dc * ( sum_s xbs[s] + xbs[c] ), 16 edges in flight ----------------
__global__ void gather1_kernel(const unsigned short* __restrict__ xbs, const int* __restrict__ offs,
                               const int* __restrict__ cnt, const int* __restrict__ csr,
                               const float* __restrict__ dis, unsigned short* __restrict__ xa, int N) {
    int node = blockIdx.x * 4 + (threadIdx.x >> 6);
    int lane = threadIdx.x & 63;
    if (node >= N) return;
    int off = offs[node], dg = cnt[node];
    int g = lane >> 4, c = lane & 15;
    const u16x8* XB = (const u16x8*)xbs;
    float acc[8] = {};
    int s0 = (g      < dg) ? csr[off + g]      : N;
    int s1 = (g + 4  < dg) ? csr[off + g + 4]  : N;
    int s2 = (g + 8  < dg) ? csr[off + g + 8]  : N;
    int s3 = (g + 12 < dg) ? csr[off + g + 12] : N;
    for (int j = 0; j < dg; j += 16) {
        int jb = j + 16;
        int t0 = (jb + g      < dg) ? csr[off + jb + g]      : N;
        int t1 = (jb + g + 4  < dg) ? csr[off + jb + g + 4]  : N;
        int t2 = (jb + g + 8  < dg) ? csr[off + jb + g + 8]  : N;
        int t3 = (jb + g + 12 < dg) ? csr[off + jb + g + 12] : N;
        u16x8 v0 = XB[(size_t)s0 * 16 + c];
        u16x8 v1 = XB[(size_t)s1 * 16 + c];
        u16x8 v2 = XB[(size_t)s2 * 16 + c];
        u16x8 v3 = XB[(size_t)s3 * 16 + c];
#pragma unroll
        for (int k = 0; k < 8; k++)
            acc[k] += (bf2f(v0[k]) + bf2f(v1[k])) + (bf2f(v2[k]) + bf2f(v3[k]));
        s0 = t0; s1 = t1; s2 = t2; s3 = t3;
    }
#pragma unroll
    for (int k = 0; k < 8; k++) {
        acc[k] += __shfl_xor(acc[k], 16);
        acc[k] += __shfl_xor(acc[k], 32);
    }
    float dc = dis[node];
    u16x8 xv = XB[(size_t)node * 16 + c];
    if (lane < 16) {
        u16x8 o;
#pragma unroll
        for (int k = 0; k < 8; k++) o[k] = f2bf(dc * (acc[k] + bf2f(xv[k])));
        ((u16x8*)xa)[(size_t)node * 16 + c] = o;
    }
}

// ---------------- fused MLP (MFMA): h2s = dis .* relu(xa@W1+b1) @ W2 ----------------
__global__ __launch_bounds__(256) void mlp_kernel(const unsigned short* __restrict__ xa,
                                                  const unsigned short* __restrict__ w1p,
                                                  const unsigned short* __restrict__ w2p,
                                                  const float* __restrict__ b1,
                                                  const float* __restrict__ dis,
                                                  unsigned short* __restrict__ h2s, int N) {
    __shared__ unsigned short a1s[64][136];
    int wv = threadIdx.x >> 6;
    int l = threadIdx.x & 63;
    int row16 = l & 15, kg = l >> 4;
    int n0 = blockIdx.x * 64;
    int rbase = n0 + wv * 16;

    f32x4 acc[8];
#pragma unroll
    for (int ct = 0; ct < 8; ct++) acc[ct] = (f32x4)0.f;
    int r = rbase + row16;
    int rc = (r < N) ? r : (N - 1);
#pragma unroll
    for (int kc = 0; kc < 4; kc++) {
        s16x8 af = *(const s16x8*)(xa + (size_t)rc * 128 + kc * 32 + kg * 8);
#pragma unroll
        for (int ct = 0; ct < 8; ct++) {
            s16x8 bf = *(const s16x8*)(w1p + (size_t)((ct * 4 + kc) * 64 + l) * 8);
            acc[ct] = __builtin_amdgcn_mfma_f32_16x16x32_bf16(af, bf, acc[ct], 0, 0, 0);
        }
    }
#pragma unroll
    for (int ct = 0; ct < 8; ct++) {
        float bb = b1[ct * 16 + row16];
#pragma unroll
        for (int v = 0; v < 4; v++)
            a1s[wv * 16 + kg * 4 + v][ct * 16 + row16] = f2bf(fmaxf(acc[ct][v] + bb, 0.f));
    }
    __syncthreads();

    f32x4 acc2[3];
#pragma unroll
    for (int ct = 0; ct < 3; ct++) acc2[ct] = (f32x4)0.f;
#pragma unroll
    for (int kc = 0; kc < 4; kc++) {
        s16x8 af = *(const s16x8*)&a1s[wv * 16 + row16][kc * 32 + kg * 8];
#pragma unroll
        for (int ct = 0; ct < 3; ct++) {
            s16x8 bf = *(const s16x8*)(w2p + (size_t)((ct * 4 + kc) * 64 + l) * 8);
            acc2[ct] = __builtin_amdgcn_mfma_f32_16x16x32_bf16(af, bf, acc2[ct], 0, 0, 0);
        }
    }
#pragma unroll
    for (int v = 0; v < 4; v++) {
        int rr = rbase + kg * 4 + v;
        if (rr < N) {
            float d = dis[rr];
#pragma unroll
            for (int ct = 0; ct < 3; ct++)
                h2s[(size_t)rr * 64 + ct * 16 + row16] = f2bf(d * acc2[ct][v]);
        }
    }
}

// ---------------- gather2: log_softmax(dc*(sum_s h2s[s] + h2s[node]) + b2) ----------------
// 3 groups x 20 lanes (cols as u32), 4 slots -> 12 edges in flight
__global__ void gather2_kernel(const unsigned short* __restrict__ h2s, const int* __restrict__ offs,
                               const int* __restrict__ cnt, const int* __restrict__ csr,
                               const float* __restrict__ dis, const float* __restrict__ b2,
                               float* __restrict__ out, int N) {
    int node = blockIdx.x * 4 + (threadIdx.x >> 6);
    int lane = threadIdx.x & 63;
    if (node >= N) return;
    int off = offs[node], dg = cnt[node];
    int c = lane % 20;
    int g = lane / 20;
    if (g == 3) g = 2;  // lanes 60-63 duplicate group 2 (loads coalesce, results unused)
    const unsigned* H32 = (const unsigned*)h2s;
    float a0 = 0.f, a1 = 0.f;
    int s0 = (g     < dg) ? csr[off + g]     : N;
    int s1 = (g + 3 < dg) ? csr[off + g + 3] : N;
    int s2 = (g + 6 < dg) ? csr[off + g + 6] : N;
    int s3 = (g + 9 < dg) ? csr[off + g + 9] : N;
    for (int j = 0; j < dg; j += 12) {
        int jb = j + 12;
        int t0 = (jb + g     < dg) ? csr[off + jb + g]     : N;
        int t1 = (jb + g + 3 < dg) ? csr[off + jb + g + 3] : N;
        int t2 = (jb + g + 6 < dg) ? csr[off + jb + g + 6] : N;
        int t3 = (jb + g + 9 < dg) ? csr[off + jb + g + 9] : N;
        unsigned u0 = H32[(size_t)s0 * 32 + c];
        unsigned u1 = H32[(size_t)s1 * 32 + c];
        unsigned u2 = H32[(size_t)s2 * 32 + c];
        unsigned u3 = H32[(size_t)s3 * 32 + c];
        a0 += (bf2f(u0 & 0xffffu) + bf2f(u1 & 0xffffu)) + (bf2f(u2 & 0xffffu) + bf2f(u3 & 0xffffu));
        a1 += (bf2f(u0 >> 16) + bf2f(u1 >> 16)) + (bf2f(u2 >> 16) + bf2f(u3 >> 16));
        s0 = t0; s1 = t1; s2 = t2; s3 = t3;
    }
    // fold 3 groups: col-c totals land on lanes 0..19
    float b0 = __shfl(a0, lane + 20);
    float b1_ = __shfl(a0, lane + 40);
    a0 = a0 + b0 + b1_;
    b0 = __shfl(a1, lane + 20);
    b1_ = __shfl(a1, lane + 40);
    a1 = a1 + b0 + b1_;

    float dc = dis[node];
    bool act = lane < 20;
    unsigned u = H32[(size_t)node * 32 + c];
    float v0 = act ? (dc * (a0 + bf2f(u & 0xffffu)) + b2[2 * c]) : -INFINITY;
    float v1 = act ? (dc * (a1 + bf2f(u >> 16)) + b2[2 * c + 1]) : -INFINITY;
    float m = fmaxf(v0, v1);
#pragma unroll
    for (int o = 32; o > 0; o >>= 1) m = fmaxf(m, __shfl_xor(m, o));
    float ex = act ? (__expf(v0 - m) + __expf(v1 - m)) : 0.f;
#pragma unroll
    for (int o = 32; o > 0; o >>= 1) ex += __shfl_xor(ex, o);
    float ls = __logf(ex);  // values live only on lanes 0-19 -> single-counted
    if (act) {
        float2 o2 = make_float2(v0 - m - ls, v1 - m - ls);
        ((float2*)(out + (size_t)node * 40))[c] = o2;
    }
}

extern "C" void kernel_launch(void* const* d_in, const int* in_sizes, int n_in,
                              void* d_out, int out_size, void* d_ws, size_t ws_size,
                              hipStream_t stream) {
    const float* x  = (const float*)d_in[0];
    const int*   ei = (const int*)d_in[1];
    const float* W1 = (const float*)d_in[2];
    const float* b1 = (const float*)d_in[3];
    const float* W2 = (const float*)d_in[4];
    const float* b2 = (const float*)d_in[5];
    float* out = (float*)d_out;

    const int N = in_sizes[0] / 128;
    const int E = in_sizes[1] / 2;
    const int* row = ei;
    const int* col = ei + E;

    const int Npad = (N + 511) & ~511;
    const int Epad = (E + 511) & ~511;
    const int NB = (N + 255) >> 8;  // coarse buckets (col>>8); <=512

    int* cnt      = (int*)d_ws;           // Npad
    int* offs     = cnt + Npad;           // Npad
    int* btot     = offs + Npad;          // 512
    int* boffs    = btot + 512;           // 513 (pad 1024)
    int* bcur     = boffs + 1024;         // 512
    int* csr      = bcur + 512;           // Epad
    unsigned* tmp = (unsigned*)(csr + Epad);              // Epad
    float* dis    = (float*)(tmp + Epad); // Npad
    unsigned short* w1p = (unsigned short*)(dis + Npad);  // 16384
    unsigned short* w2p = w1p + 16384;                    // 6144 (pad 8192)
    unsigned short* xbs = w2p + 8192;                     // (N+1)*128 bf16
    unsigned short* xa  = xbs + (size_t)(N + 1) * 128;    // N*128 bf16
    unsigned short* h2s = xa + (size_t)N * 128;           // (N+1)*64 bf16

    // 1) CSR build: bucket histogram -> bucket scan -> bin -> per-bucket count/scan/scatter
    hipMemsetAsync(btot, 0, 512 * sizeof(int), stream);
    hist_kernel<<<(E + BIN_TILE - 1) / BIN_TILE, 256, 0, stream>>>(col, btot, E, NB);
    bscan_kernel<<<1, 512, 0, stream>>>(btot, boffs, bcur, NB, E);
    bin_kernel<<<(E + BIN_TILE - 1) / BIN_TILE, 256, 0, stream>>>(row, col, bcur, tmp, E, NB);
    bucket_kernel<<<NB, 256, 0, stream>>>(tmp, boffs, cnt, offs, dis, csr, N);

    // 2) weight packs + h2s sentinel + pre-scaled bf16 features
    w1pack_kernel<<<8, 256, 0, stream>>>(W1, w1p);
    w2pack_kernel<<<3, 256, 0, stream>>>(W2, w2p);
    zrow_kernel<<<1, 64, 0, stream>>>((unsigned*)(h2s + (size_t)N * 64));
    {
        long total8 = (long)(N + 1) * 16;
        scale_cvt_kernel<<<(int)((total8 + 255) / 256), 256, 0, stream>>>(x, dis, xbs, N);
    }

    // 3) xa = Dc * (sum + self) on pre-scaled rows
    gather1_kernel<<<(N + 3) / 4, 256, 0, stream>>>(xbs, offs, cnt, csr, dis, xa, N);

    // 4) h2s = dis .* (relu(xa@W1+b1) @ W2)   (fused, a1 only in LDS)
    mlp_kernel<<<(N + 63) / 64, 256, 0, stream>>>(xa, w1p, w2p, b1, dis, h2s, N);

    // 5) out = log_softmax(dc*(sum + self) + b2)
    gather2_kernel<<<(N + 3) / 4, 256, 0, stream>>>(h2s, offs, cnt, csr, dis, b2, out, N);
}